// Round 1
// baseline (3602.670 us; speedup 1.0000x reference)
//
#include <hip/hip_runtime.h>
#include <hip/hip_bf16.h>
#include <stdint.h>

#define N_NODESC 25000
#define N_EDGESC 400000
#define N_GRAPHSC 64
#define F_INC 128
#define HIDC 512

typedef __attribute__((ext_vector_type(8))) short short8;
typedef __attribute__((ext_vector_type(4))) float f32x4;

__device__ __forceinline__ float bf2f(unsigned short u) {
  return __uint_as_float(((unsigned)u) << 16);
}
__device__ __forceinline__ unsigned short f2bf(float f) {
  unsigned u = __float_as_uint(f);
  u += 0x7fffu + ((u >> 16) & 1u);
  return (unsigned short)(u >> 16);
}

// ---------------- edge scatter, layer 1: agg1 += w_e * x[src] (fp32, F=128)
__global__ void edge_scatter1(const float* __restrict__ x, const int* __restrict__ ei,
                              const float* __restrict__ ea, float* __restrict__ agg1) {
  int gid = blockIdx.x * blockDim.x + threadIdx.x;
  int e = gid >> 5;          // 32 lanes / edge
  int c = gid & 31;          // float4 chunk
  int src = ei[e];
  int dst = ei[N_EDGESC + e];
  float w = ea[e];
  float4 v = *(const float4*)(x + (size_t)src * F_INC + c * 4);
  float* d = agg1 + (size_t)dst * F_INC + c * 4;
  atomicAdd(d + 0, v.x * w);
  atomicAdd(d + 1, v.y * w);
  atomicAdd(d + 2, v.z * w);
  atomicAdd(d + 3, v.w * w);
}

// ---------------- edge scatter, layer 2: agg2 += w_e * h1[src] (h1 bf16, F=512)
__global__ void edge_scatter2(const unsigned short* __restrict__ h1, const int* __restrict__ ei,
                              const float* __restrict__ ea, float* __restrict__ agg2) {
  long long gid = (long long)blockIdx.x * blockDim.x + threadIdx.x;
  int e = (int)(gid >> 7);   // 128 lanes / edge
  int c = (int)(gid & 127);  // 4 bf16 per lane
  int src = ei[e];
  int dst = ei[N_EDGESC + e];
  float w = ea[e];
  ushort4 v = *(const ushort4*)(h1 + (size_t)src * HIDC + c * 4);
  float* d = agg2 + (size_t)dst * HIDC + c * 4;
  atomicAdd(d + 0, bf2f(v.x) * w);
  atomicAdd(d + 1, bf2f(v.y) * w);
  atomicAdd(d + 2, bf2f(v.z) * w);
  atomicAdd(d + 3, bf2f(v.w) * w);
}

// ---------------- fp32 -> bf16 bulk convert (n % 4 == 0)
__global__ void f32_to_bf16(const float* __restrict__ src, unsigned short* __restrict__ dst, int n) {
  int i = (blockIdx.x * blockDim.x + threadIdx.x) * 4;
  if (i >= n) return;
  float4 v = *(const float4*)(src + i);
  ushort4 o;
  o.x = f2bf(v.x); o.y = f2bf(v.y); o.z = f2bf(v.z); o.w = f2bf(v.w);
  *(ushort4*)(dst + i) = o;
}

// ---------------- build B^T (bf16): WT[n][k] = k<S ? Wrel[k][n] : Wroot[k-S][n], n<512, K=2S
__global__ void build_WT(const float* __restrict__ Wrel, const float* __restrict__ Wroot,
                         unsigned short* __restrict__ WT, int S) {
  int K = 2 * S;
  int gid = blockIdx.x * blockDim.x + threadIdx.x;
  if (gid >= 512 * K) return;
  int n = gid / K;
  int k = gid - n * K;
  float v = (k < S) ? Wrel[(size_t)k * 512 + n] : Wroot[(size_t)(k - S) * 512 + n];
  WT[gid] = f2bf(v);
}

// ---------------- bf16 MFMA GEMM: Out = relu([A0|A1] @ BT^T + bias), Out bf16 [M][512]
// A0/A1: bf16 [M][S] row-major (K = 2S). BT: bf16 [512][K] row-major. 128x128x64 tiles,
// 4 waves (2x2), 16x16x32 MFMA, global_load_lds width-16 with XOR-swizzled LDS chunks.
__global__ __launch_bounds__(256, 2)
void gemm_bt_relu(const short* __restrict__ A0, const short* __restrict__ A1,
                  const short* __restrict__ BT, const float* __restrict__ bias,
                  unsigned short* __restrict__ Out, int M, int S) {
  const int K = 2 * S;
  __shared__ __align__(16) short As[128 * 64];
  __shared__ __align__(16) short Bs[128 * 64];
  const int m0 = blockIdx.x * 128;
  const int n0 = blockIdx.y * 128;
  const int tid = threadIdx.x;
  const int wave = tid >> 6;
  const int lane = tid & 63;
  const int quad = lane >> 4;
  const int r = lane & 15;
  const int wm = (wave >> 1) * 64;
  const int wn = (wave & 1) * 64;

  f32x4 acc[4][4] = {};

  const int nk = K >> 6;
  for (int kt = 0; kt < nk; ++kt) {
    const int kbase = kt << 6;
    const short* Ab;
    int koff;
    if (kbase < S) { Ab = A0; koff = kbase; } else { Ab = A1; koff = kbase - S; }
#pragma unroll
    for (int i = 0; i < 4; ++i) {
      int s = ((wave * 4 + i) << 6) + lane;     // 16B slot index
      int row = s >> 3;                          // tile row (m)
      int c = (s & 7) ^ (row & 7);               // global chunk (XOR swizzle)
      int rg = m0 + row; if (rg > M - 1) rg = M - 1;   // clamp OOB rows (discarded at store)
      const short* gp = Ab + (size_t)rg * S + koff + (c << 3);
      __builtin_amdgcn_global_load_lds((const __attribute__((address_space(1))) void*)gp,
                                       (__attribute__((address_space(3))) void*)&As[(wave * 4 + i) * 512],
                                       16, 0, 0);
    }
#pragma unroll
    for (int i = 0; i < 4; ++i) {
      int s = ((wave * 4 + i) << 6) + lane;
      int row = s >> 3;                          // tile row (n)
      int c = (s & 7) ^ (row & 7);
      const short* gp = BT + (size_t)(n0 + row) * K + kbase + (c << 3);
      __builtin_amdgcn_global_load_lds((const __attribute__((address_space(1))) void*)gp,
                                       (__attribute__((address_space(3))) void*)&Bs[(wave * 4 + i) * 512],
                                       16, 0, 0);
    }
    __syncthreads();
#pragma unroll
    for (int ks = 0; ks < 2; ++ks) {
      short8 af[4], bfr[4];
#pragma unroll
      for (int tm = 0; tm < 4; ++tm) {
        int ml = wm + tm * 16 + r;
        int c = (ks << 2) + quad;
        int slot = ml * 8 + (c ^ (ml & 7));
        af[tm] = *(const short8*)&As[slot * 8];
      }
#pragma unroll
      for (int tn = 0; tn < 4; ++tn) {
        int nl = wn + tn * 16 + r;
        int c = (ks << 2) + quad;
        int slot = nl * 8 + (c ^ (nl & 7));
        bfr[tn] = *(const short8*)&Bs[slot * 8];
      }
#pragma unroll
      for (int tm = 0; tm < 4; ++tm)
#pragma unroll
        for (int tn = 0; tn < 4; ++tn)
          acc[tm][tn] = __builtin_amdgcn_mfma_f32_16x16x32_bf16(af[tm], bfr[tn], acc[tm][tn], 0, 0, 0);
    }
    __syncthreads();
  }

#pragma unroll
  for (int tm = 0; tm < 4; ++tm) {
    int rowb = m0 + wm + tm * 16 + quad * 4;
#pragma unroll
    for (int tn = 0; tn < 4; ++tn) {
      int col = n0 + wn + tn * 16 + r;
      float bv = bias[col];
#pragma unroll
      for (int reg = 0; reg < 4; ++reg) {
        int rr = rowb + reg;
        if (rr < M) {
          float v = acc[tm][tn][reg] + bv;
          v = v > 0.f ? v : 0.f;
          Out[(size_t)rr * HIDC + col] = f2bf(v);
        }
      }
    }
  }
}

// ---------------- mean pool per graph (batch_ids sorted -> binary search ranges)
__global__ void pool_kernel(const unsigned short* __restrict__ h2, const int* __restrict__ batch,
                            float* __restrict__ g) {
  int gi = blockIdx.x;
  int t = threadIdx.x;  // 256 threads, 2 cols each
  int lo = 0, hi = N_NODESC;
  while (lo < hi) { int mid = (lo + hi) >> 1; if (batch[mid] < gi) lo = mid + 1; else hi = mid; }
  int start = lo;
  hi = N_NODESC;
  while (lo < hi) { int mid = (lo + hi) >> 1; if (batch[mid] < gi + 1) lo = mid + 1; else hi = mid; }
  int end = lo;
  float a0 = 0.f, a1 = 0.f;
  for (int nd = start; nd < end; ++nd) {
    ushort2 v = *(const ushort2*)(h2 + (size_t)nd * HIDC + t * 2);
    a0 += bf2f(v.x);
    a1 += bf2f(v.y);
  }
  float inv = 1.0f / fmaxf((float)(end - start), 1.0f);
  g[gi * HIDC + t * 2] = a0 * inv;
  g[gi * HIDC + t * 2 + 1] = a1 * inv;
}

// ---------------- tiny MLP head: 512 -> 64 -> 16 -> 1 per graph (fp32)
__global__ void mlp_kernel(const float* __restrict__ g, const float* __restrict__ Wl1,
                           const float* __restrict__ bl1, const float* __restrict__ Wl2,
                           const float* __restrict__ bl2, const float* __restrict__ Wl3,
                           const float* __restrict__ bl3, float* __restrict__ out) {
  int gi = blockIdx.x;
  int t = threadIdx.x;  // 64 threads
  __shared__ float h1s[64];
  __shared__ float h2s[16];
  const float* gr = g + gi * HIDC;
  float acc = bl1[t];
  for (int j = 0; j < 512; ++j) acc += gr[j] * Wl1[j * 64 + t];
  h1s[t] = fmaxf(acc, 0.f);
  __syncthreads();
  if (t < 16) {
    float a = bl2[t];
    for (int j = 0; j < 64; ++j) a += h1s[j] * Wl2[j * 16 + t];
    h2s[t] = fmaxf(a, 0.f);
  }
  __syncthreads();
  if (t == 0) {
    float a = bl3[0];
    for (int j = 0; j < 16; ++j) a += h2s[j] * Wl3[j];
    out[gi] = a;
  }
}

extern "C" void kernel_launch(void* const* d_in, const int* in_sizes, int n_in,
                              void* d_out, int out_size, void* d_ws, size_t ws_size,
                              hipStream_t stream) {
  const float* x      = (const float*)d_in[0];
  const int*   ei     = (const int*)d_in[1];
  const float* ea     = (const float*)d_in[2];
  const int*   batch  = (const int*)d_in[3];
  const float* W1rel  = (const float*)d_in[4];
  const float* b1     = (const float*)d_in[5];
  const float* W1root = (const float*)d_in[6];
  const float* W2rel  = (const float*)d_in[7];
  const float* b2     = (const float*)d_in[8];
  const float* W2root = (const float*)d_in[9];
  const float* Wl1    = (const float*)d_in[10];
  const float* bl1    = (const float*)d_in[11];
  const float* Wl2    = (const float*)d_in[12];
  const float* bl2    = (const float*)d_in[13];
  const float* Wl3    = (const float*)d_in[14];
  const float* bl3    = (const float*)d_in[15];
  float* out = (float*)d_out;

  // workspace layout (lifetime-overlapped):
  // [0, 51.2M): agg1 fp32 (12.8M) | agg1bf (6.4M @12.8M) | xbf (6.4M @19.2M)
  //             -> then agg2 fp32 (51.2M) -> then h2 bf16 (25.6M)
  // [51.2M, 76.8M): h1 bf16
  // [76.8M, 102.4M): agg2bf bf16
  // [102.4M, ~103.9M): W1T, W2T, gpool
  char* ws = (char*)d_ws;
  float*          agg1   = (float*)(ws + 0);
  unsigned short* agg1bf = (unsigned short*)(ws + 12800000);
  unsigned short* xbf    = (unsigned short*)(ws + 19200000);
  float*          agg2   = (float*)(ws + 0);
  unsigned short* h2     = (unsigned short*)(ws + 0);
  unsigned short* h1     = (unsigned short*)(ws + 51200000);
  unsigned short* agg2bf = (unsigned short*)(ws + 76800000);
  unsigned short* W1T    = (unsigned short*)(ws + 102400000);
  unsigned short* W2T    = (unsigned short*)(ws + 102662144);
  float*          gpool  = (float*)(ws + 103710720);

  // 1) layer-1 aggregation (fp32 atomics, 128-dim)
  hipMemsetAsync(agg1, 0, (size_t)N_NODESC * F_INC * 4, stream);
  edge_scatter1<<<(N_EDGESC * 32) / 256, 256, 0, stream>>>(x, ei, ea, agg1);

  // 2) conversions for GEMM1 (+ both weight transposes)
  f32_to_bf16<<<(N_NODESC * F_INC / 4 + 255) / 256, 256, 0, stream>>>(x, xbf, N_NODESC * F_INC);
  f32_to_bf16<<<(N_NODESC * F_INC / 4 + 255) / 256, 256, 0, stream>>>(agg1, agg1bf, N_NODESC * F_INC);
  build_WT<<<(512 * 256 + 255) / 256, 256, 0, stream>>>(W1rel, W1root, W1T, 128);
  build_WT<<<(512 * 1024 + 255) / 256, 256, 0, stream>>>(W2rel, W2root, W2T, 512);

  // 3) GEMM1: h1 = relu([agg1|x] @ [W1rel;W1root] + b1)   (M=25000, K=256, N=512)
  dim3 gg((N_NODESC + 127) / 128, 4);
  gemm_bt_relu<<<gg, 256, 0, stream>>>((const short*)agg1bf, (const short*)xbf,
                                       (const short*)W1T, b1, h1, N_NODESC, 128);

  // 4) layer-2 aggregation (fp32 atomics, 512-dim, gathers bf16 h1 rows)
  hipMemsetAsync(agg2, 0, (size_t)N_NODESC * HIDC * 4, stream);
  edge_scatter2<<<(N_EDGESC * 128) / 256, 256, 0, stream>>>(h1, ei, ea, agg2);
  f32_to_bf16<<<(N_NODESC * HIDC / 4 + 255) / 256, 256, 0, stream>>>(agg2, agg2bf, N_NODESC * HIDC);

  // 5) GEMM2: h2 = relu([agg2|h1] @ [W2rel;W2root] + b2)   (M=25000, K=1024, N=512)
  gemm_bt_relu<<<gg, 256, 0, stream>>>((const short*)agg2bf, (const short*)h1,
                                       (const short*)W2T, b2, h2, N_NODESC, 512);

  // 6) mean pool + MLP head
  pool_kernel<<<N_GRAPHSC, 256, 0, stream>>>(h2, batch, gpool);
  mlp_kernel<<<N_GRAPHSC, 64, 0, stream>>>(gpool, Wl1, bl1, Wl2, bl2, Wl3, bl3, out);
}

// Round 2
// 482.567 us; speedup vs baseline: 7.4656x; 7.4656x over previous
//
#include <hip/hip_runtime.h>
#include <hip/hip_bf16.h>
#include <stdint.h>

#define N_NODESC 25000
#define N_EDGESC 400000
#define N_GRAPHSC 64
#define F_INC 128
#define HIDC 512

typedef __attribute__((ext_vector_type(8))) short short8;
typedef __attribute__((ext_vector_type(8))) unsigned short ushort8;
typedef __attribute__((ext_vector_type(4))) float f32x4;

__device__ __forceinline__ float bf2f(unsigned short u) {
  return __uint_as_float(((unsigned)u) << 16);
}
__device__ __forceinline__ unsigned short f2bf(float f) {
  unsigned u = __float_as_uint(f);
  u += 0x7fffu + ((u >> 16) & 1u);
  return (unsigned short)(u >> 16);
}

// ================= CSR build (per launch; ~800K int atomics total) =================
__global__ void deg_kernel(const int* __restrict__ ei, int* __restrict__ deg) {
  int e = blockIdx.x * blockDim.x + threadIdx.x;
  if (e >= N_EDGESC) return;
  atomicAdd(&deg[ei[N_EDGESC + e]], 1);
}

// single-block exclusive scan of deg[25000] -> indptr[25001], copy to cursor
__global__ __launch_bounds__(1024)
void scan_kernel(const int* __restrict__ deg, int* __restrict__ indptr, int* __restrict__ cursor) {
  __shared__ int sums[1024];
  const int t = threadIdx.x;
  const int CH = (N_NODESC + 1023) / 1024;  // 25
  const int base = t * CH;
  int s = 0;
  for (int i = 0; i < CH; ++i) {
    int idx = base + i;
    if (idx < N_NODESC) s += deg[idx];
  }
  sums[t] = s;
  __syncthreads();
  for (int off = 1; off < 1024; off <<= 1) {
    int v = (t >= off) ? sums[t - off] : 0;
    __syncthreads();
    sums[t] += v;
    __syncthreads();
  }
  int run = (t > 0) ? sums[t - 1] : 0;
  for (int i = 0; i < CH; ++i) {
    int idx = base + i;
    if (idx < N_NODESC) {
      indptr[idx] = run;
      cursor[idx] = run;
      run += deg[idx];
    }
  }
  if (t == 0) indptr[N_NODESC] = sums[1023];
}

__global__ void fill_kernel(const int* __restrict__ ei, const float* __restrict__ ea,
                            int* __restrict__ cursor, int* __restrict__ esrc,
                            float* __restrict__ ew) {
  int e = blockIdx.x * blockDim.x + threadIdx.x;
  if (e >= N_EDGESC) return;
  int dst = ei[N_EDGESC + e];
  int pos = atomicAdd(&cursor[dst], 1);
  esrc[pos] = ei[e];
  ew[pos] = ea[e];
}

// ================= CSR gather aggregation (no atomics) =================
// layer 1: one wave per node, F=128 fp32 in, bf16 out. lane holds 2 cols (float2).
__global__ __launch_bounds__(256)
void agg_gather1(const float* __restrict__ x, const int* __restrict__ indptr,
                 const int* __restrict__ esrc, const float* __restrict__ ew,
                 unsigned short* __restrict__ aggbf) {
  int node = blockIdx.x * 4 + (threadIdx.x >> 6);
  if (node >= N_NODESC) return;
  int lane = threadIdx.x & 63;
  int beg = indptr[node], end = indptr[node + 1];
  float a0 = 0.f, a1 = 0.f;
  for (int j = beg; j < end; ++j) {
    int s = esrc[j];
    float w = ew[j];
    float2 v = *(const float2*)(x + (size_t)s * F_INC + lane * 2);
    a0 += v.x * w;
    a1 += v.y * w;
  }
  ushort2 o;
  o.x = f2bf(a0);
  o.y = f2bf(a1);
  *(ushort2*)(aggbf + (size_t)node * F_INC + lane * 2) = o;
}

// layer 2: one wave per node, F=512 bf16 in, bf16 out. lane holds 8 cols (16B).
__global__ __launch_bounds__(256)
void agg_gather2(const unsigned short* __restrict__ h1, const int* __restrict__ indptr,
                 const int* __restrict__ esrc, const float* __restrict__ ew,
                 unsigned short* __restrict__ aggbf) {
  int node = blockIdx.x * 4 + (threadIdx.x >> 6);
  if (node >= N_NODESC) return;
  int lane = threadIdx.x & 63;
  int beg = indptr[node], end = indptr[node + 1];
  float acc[8] = {};
  for (int j = beg; j < end; ++j) {
    int s = esrc[j];
    float w = ew[j];
    ushort8 v = *(const ushort8*)(h1 + (size_t)s * HIDC + lane * 8);
#pragma unroll
    for (int c = 0; c < 8; ++c) acc[c] += bf2f(v[c]) * w;
  }
  ushort8 o;
#pragma unroll
  for (int c = 0; c < 8; ++c) o[c] = f2bf(acc[c]);
  *(ushort8*)(aggbf + (size_t)node * HIDC + lane * 8) = o;
}

// ---------------- fp32 -> bf16 bulk convert (n % 4 == 0)
__global__ void f32_to_bf16(const float* __restrict__ src, unsigned short* __restrict__ dst, int n) {
  int i = (blockIdx.x * blockDim.x + threadIdx.x) * 4;
  if (i >= n) return;
  float4 v = *(const float4*)(src + i);
  ushort4 o;
  o.x = f2bf(v.x); o.y = f2bf(v.y); o.z = f2bf(v.z); o.w = f2bf(v.w);
  *(ushort4*)(dst + i) = o;
}

// ---------------- build B^T (bf16): WT[n][k] = k<S ? Wrel[k][n] : Wroot[k-S][n], n<512, K=2S
__global__ void build_WT(const float* __restrict__ Wrel, const float* __restrict__ Wroot,
                         unsigned short* __restrict__ WT, int S) {
  int K = 2 * S;
  int gid = blockIdx.x * blockDim.x + threadIdx.x;
  if (gid >= 512 * K) return;
  int n = gid / K;
  int k = gid - n * K;
  float v = (k < S) ? Wrel[(size_t)k * 512 + n] : Wroot[(size_t)(k - S) * 512 + n];
  WT[gid] = f2bf(v);
}

// ---------------- bf16 MFMA GEMM: Out = relu([A0|A1] @ BT^T + bias), Out bf16 [M][512]
__global__ __launch_bounds__(256, 2)
void gemm_bt_relu(const short* __restrict__ A0, const short* __restrict__ A1,
                  const short* __restrict__ BT, const float* __restrict__ bias,
                  unsigned short* __restrict__ Out, int M, int S) {
  const int K = 2 * S;
  __shared__ __align__(16) short As[128 * 64];
  __shared__ __align__(16) short Bs[128 * 64];
  const int m0 = blockIdx.x * 128;
  const int n0 = blockIdx.y * 128;
  const int tid = threadIdx.x;
  const int wave = tid >> 6;
  const int lane = tid & 63;
  const int quad = lane >> 4;
  const int r = lane & 15;
  const int wm = (wave >> 1) * 64;
  const int wn = (wave & 1) * 64;

  f32x4 acc[4][4] = {};

  const int nk = K >> 6;
  for (int kt = 0; kt < nk; ++kt) {
    const int kbase = kt << 6;
    const short* Ab;
    int koff;
    if (kbase < S) { Ab = A0; koff = kbase; } else { Ab = A1; koff = kbase - S; }
#pragma unroll
    for (int i = 0; i < 4; ++i) {
      int s = ((wave * 4 + i) << 6) + lane;     // 16B slot index
      int row = s >> 3;                          // tile row (m)
      int c = (s & 7) ^ (row & 7);               // global chunk (XOR swizzle)
      int rg = m0 + row; if (rg > M - 1) rg = M - 1;   // clamp OOB rows (discarded at store)
      const short* gp = Ab + (size_t)rg * S + koff + (c << 3);
      __builtin_amdgcn_global_load_lds((const __attribute__((address_space(1))) void*)gp,
                                       (__attribute__((address_space(3))) void*)&As[(wave * 4 + i) * 512],
                                       16, 0, 0);
    }
#pragma unroll
    for (int i = 0; i < 4; ++i) {
      int s = ((wave * 4 + i) << 6) + lane;
      int row = s >> 3;                          // tile row (n)
      int c = (s & 7) ^ (row & 7);
      const short* gp = BT + (size_t)(n0 + row) * K + kbase + (c << 3);
      __builtin_amdgcn_global_load_lds((const __attribute__((address_space(1))) void*)gp,
                                       (__attribute__((address_space(3))) void*)&Bs[(wave * 4 + i) * 512],
                                       16, 0, 0);
    }
    __syncthreads();
#pragma unroll
    for (int ks = 0; ks < 2; ++ks) {
      short8 af[4], bfr[4];
#pragma unroll
      for (int tm = 0; tm < 4; ++tm) {
        int ml = wm + tm * 16 + r;
        int c = (ks << 2) + quad;
        int slot = ml * 8 + (c ^ (ml & 7));
        af[tm] = *(const short8*)&As[slot * 8];
      }
#pragma unroll
      for (int tn = 0; tn < 4; ++tn) {
        int nl = wn + tn * 16 + r;
        int c = (ks << 2) + quad;
        int slot = nl * 8 + (c ^ (nl & 7));
        bfr[tn] = *(const short8*)&Bs[slot * 8];
      }
#pragma unroll
      for (int tm = 0; tm < 4; ++tm)
#pragma unroll
        for (int tn = 0; tn < 4; ++tn)
          acc[tm][tn] = __builtin_amdgcn_mfma_f32_16x16x32_bf16(af[tm], bfr[tn], acc[tm][tn], 0, 0, 0);
    }
    __syncthreads();
  }

#pragma unroll
  for (int tm = 0; tm < 4; ++tm) {
    int rowb = m0 + wm + tm * 16 + quad * 4;
#pragma unroll
    for (int tn = 0; tn < 4; ++tn) {
      int col = n0 + wn + tn * 16 + r;
      float bv = bias[col];
#pragma unroll
      for (int reg = 0; reg < 4; ++reg) {
        int rr = rowb + reg;
        if (rr < M) {
          float v = acc[tm][tn][reg] + bv;
          v = v > 0.f ? v : 0.f;
          Out[(size_t)rr * HIDC + col] = f2bf(v);
        }
      }
    }
  }
}

// ---------------- mean pool per graph (batch_ids sorted -> binary search ranges)
__global__ void pool_kernel(const unsigned short* __restrict__ h2, const int* __restrict__ batch,
                            float* __restrict__ g) {
  int gi = blockIdx.x;
  int t = threadIdx.x;  // 256 threads, 2 cols each
  int lo = 0, hi = N_NODESC;
  while (lo < hi) { int mid = (lo + hi) >> 1; if (batch[mid] < gi) lo = mid + 1; else hi = mid; }
  int start = lo;
  hi = N_NODESC;
  while (lo < hi) { int mid = (lo + hi) >> 1; if (batch[mid] < gi + 1) lo = mid + 1; else hi = mid; }
  int end = lo;
  float a0 = 0.f, a1 = 0.f;
  for (int nd = start; nd < end; ++nd) {
    ushort2 v = *(const ushort2*)(h2 + (size_t)nd * HIDC + t * 2);
    a0 += bf2f(v.x);
    a1 += bf2f(v.y);
  }
  float inv = 1.0f / fmaxf((float)(end - start), 1.0f);
  g[gi * HIDC + t * 2] = a0 * inv;
  g[gi * HIDC + t * 2 + 1] = a1 * inv;
}

// ---------------- tiny MLP head: 512 -> 64 -> 16 -> 1 per graph (fp32)
__global__ void mlp_kernel(const float* __restrict__ g, const float* __restrict__ Wl1,
                           const float* __restrict__ bl1, const float* __restrict__ Wl2,
                           const float* __restrict__ bl2, const float* __restrict__ Wl3,
                           const float* __restrict__ bl3, float* __restrict__ out) {
  int gi = blockIdx.x;
  int t = threadIdx.x;  // 64 threads
  __shared__ float h1s[64];
  __shared__ float h2s[16];
  const float* gr = g + gi * HIDC;
  float acc = bl1[t];
  for (int j = 0; j < 512; ++j) acc += gr[j] * Wl1[j * 64 + t];
  h1s[t] = fmaxf(acc, 0.f);
  __syncthreads();
  if (t < 16) {
    float a = bl2[t];
    for (int j = 0; j < 64; ++j) a += h1s[j] * Wl2[j * 16 + t];
    h2s[t] = fmaxf(a, 0.f);
  }
  __syncthreads();
  if (t == 0) {
    float a = bl3[0];
    for (int j = 0; j < 16; ++j) a += h2s[j] * Wl3[j];
    out[gi] = a;
  }
}

extern "C" void kernel_launch(void* const* d_in, const int* in_sizes, int n_in,
                              void* d_out, int out_size, void* d_ws, size_t ws_size,
                              hipStream_t stream) {
  const float* x      = (const float*)d_in[0];
  const int*   ei     = (const int*)d_in[1];
  const float* ea     = (const float*)d_in[2];
  const int*   batch  = (const int*)d_in[3];
  const float* W1rel  = (const float*)d_in[4];
  const float* b1     = (const float*)d_in[5];
  const float* W1root = (const float*)d_in[6];
  const float* W2rel  = (const float*)d_in[7];
  const float* b2     = (const float*)d_in[8];
  const float* W2root = (const float*)d_in[9];
  const float* Wl1    = (const float*)d_in[10];
  const float* bl1    = (const float*)d_in[11];
  const float* Wl2    = (const float*)d_in[12];
  const float* bl2    = (const float*)d_in[13];
  const float* Wl3    = (const float*)d_in[14];
  const float* bl3    = (const float*)d_in[15];
  float* out = (float*)d_out;

  // workspace layout (bytes, all 16B-aligned):
  char* ws = (char*)d_ws;
  unsigned short* xbf    = (unsigned short*)(ws + 0);           //  6.4 MB
  unsigned short* agg1bf = (unsigned short*)(ws + 6400000);     //  6.4 MB
  unsigned short* h1     = (unsigned short*)(ws + 12800000);    // 25.6 MB
  unsigned short* agg2bf = (unsigned short*)(ws + 38400000);    // 25.6 MB
  unsigned short* h2     = (unsigned short*)(ws + 64000000);    // 25.6 MB
  unsigned short* W1T    = (unsigned short*)(ws + 89600000);    // 256 KB
  unsigned short* W2T    = (unsigned short*)(ws + 89862144);    //   1 MB
  float*          gpool  = (float*)(ws + 90910720);             // 128 KB
  int*            deg    = (int*)(ws + 91041792);               // 100 KB
  int*            cursor = (int*)(ws + 91141792);               // 100 KB
  int*            indptr = (int*)(ws + 91241792);               // 100 KB+4
  int*            esrc   = (int*)(ws + 91341808);               //  1.6 MB
  float*          ewgt   = (float*)(ws + 92941808);             //  1.6 MB

  // 0) CSR build
  hipMemsetAsync(deg, 0, N_NODESC * sizeof(int), stream);
  deg_kernel<<<(N_EDGESC + 255) / 256, 256, 0, stream>>>(ei, deg);
  scan_kernel<<<1, 1024, 0, stream>>>(deg, indptr, cursor);
  fill_kernel<<<(N_EDGESC + 255) / 256, 256, 0, stream>>>(ei, ea, cursor, esrc, ewgt);

  // 1) layer-1 aggregation (gather, no atomics) + x conversion + weight transposes
  agg_gather1<<<(N_NODESC + 3) / 4, 256, 0, stream>>>(x, indptr, esrc, ewgt, agg1bf);
  f32_to_bf16<<<(N_NODESC * F_INC / 4 + 255) / 256, 256, 0, stream>>>(x, xbf, N_NODESC * F_INC);
  build_WT<<<(512 * 256 + 255) / 256, 256, 0, stream>>>(W1rel, W1root, W1T, 128);
  build_WT<<<(512 * 1024 + 255) / 256, 256, 0, stream>>>(W2rel, W2root, W2T, 512);

  // 2) GEMM1: h1 = relu([agg1|x] @ [W1rel;W1root] + b1)   (M=25000, K=256, N=512)
  dim3 gg((N_NODESC + 127) / 128, 4);
  gemm_bt_relu<<<gg, 256, 0, stream>>>((const short*)agg1bf, (const short*)xbf,
                                       (const short*)W1T, b1, h1, N_NODESC, 128);

  // 3) layer-2 aggregation (gather, no atomics)
  agg_gather2<<<(N_NODESC + 3) / 4, 256, 0, stream>>>(h1, indptr, esrc, ewgt, agg2bf);

  // 4) GEMM2: h2 = relu([agg2|h1] @ [W2rel;W2root] + b2)   (M=25000, K=1024, N=512)
  gemm_bt_relu<<<gg, 256, 0, stream>>>((const short*)agg2bf, (const short*)h1,
                                       (const short*)W2T, b2, h2, N_NODESC, 512);

  // 5) mean pool + MLP head
  pool_kernel<<<N_GRAPHSC, 256, 0, stream>>>(h2, batch, gpool);
  mlp_kernel<<<N_GRAPHSC, 64, 0, stream>>>(gpool, Wl1, bl1, Wl2, bl2, Wl3, bl3, out);
}

// Round 3
// 400.315 us; speedup vs baseline: 8.9996x; 1.2055x over previous
//
#include <hip/hip_runtime.h>
#include <hip/hip_bf16.h>
#include <stdint.h>

#define N_NODESC 25000
#define N_EDGESC 400000
#define N_GRAPHSC 64
#define F_INC 128
#define HIDC 512
#define POOL_SLAB 64

typedef __attribute__((ext_vector_type(8))) short short8;
typedef __attribute__((ext_vector_type(8))) unsigned short ushort8;
typedef __attribute__((ext_vector_type(4))) float f32x4;

__device__ __forceinline__ float bf2f(unsigned short u) {
  return __uint_as_float(((unsigned)u) << 16);
}
__device__ __forceinline__ unsigned short f2bf(float f) {
  unsigned u = __float_as_uint(f);
  u += 0x7fffu + ((u >> 16) & 1u);
  return (unsigned short)(u >> 16);
}

// ================= CSR build (per launch; ~800K int atomics total) =================
__global__ void deg_kernel(const int* __restrict__ ei, int* __restrict__ deg) {
  int e = blockIdx.x * blockDim.x + threadIdx.x;
  if (e >= N_EDGESC) return;
  atomicAdd(&deg[ei[N_EDGESC + e]], 1);
}

// single-block exclusive scan of deg[25000] -> indptr[25001], copy to cursor
__global__ __launch_bounds__(1024)
void scan_kernel(const int* __restrict__ deg, int* __restrict__ indptr, int* __restrict__ cursor) {
  __shared__ int sums[1024];
  const int t = threadIdx.x;
  const int CH = (N_NODESC + 1023) / 1024;  // 25
  const int base = t * CH;
  int s = 0;
  for (int i = 0; i < CH; ++i) {
    int idx = base + i;
    if (idx < N_NODESC) s += deg[idx];
  }
  sums[t] = s;
  __syncthreads();
  for (int off = 1; off < 1024; off <<= 1) {
    int v = (t >= off) ? sums[t - off] : 0;
    __syncthreads();
    sums[t] += v;
    __syncthreads();
  }
  int run = (t > 0) ? sums[t - 1] : 0;
  for (int i = 0; i < CH; ++i) {
    int idx = base + i;
    if (idx < N_NODESC) {
      indptr[idx] = run;
      cursor[idx] = run;
      run += deg[idx];
    }
  }
  if (t == 0) indptr[N_NODESC] = sums[1023];
}

__global__ void fill_kernel(const int* __restrict__ ei, const float* __restrict__ ea,
                            int* __restrict__ cursor, int* __restrict__ esrc,
                            float* __restrict__ ew) {
  int e = blockIdx.x * blockDim.x + threadIdx.x;
  if (e >= N_EDGESC) return;
  int dst = ei[N_EDGESC + e];
  int pos = atomicAdd(&cursor[dst], 1);
  esrc[pos] = ei[e];
  ew[pos] = ea[e];
}

// ================= CSR gather aggregation (no atomics) =================
// layer 1: one wave per node, F=128 fp32 in, bf16 out. lane holds 2 cols (float2).
__global__ __launch_bounds__(256)
void agg_gather1(const float* __restrict__ x, const int* __restrict__ indptr,
                 const int* __restrict__ esrc, const float* __restrict__ ew,
                 unsigned short* __restrict__ aggbf) {
  int node = blockIdx.x * 4 + (threadIdx.x >> 6);
  if (node >= N_NODESC) return;
  int lane = threadIdx.x & 63;
  int beg = indptr[node], end = indptr[node + 1];
  float a0 = 0.f, a1 = 0.f;
  for (int j = beg; j < end; ++j) {
    int s = esrc[j];
    float w = ew[j];
    float2 v = *(const float2*)(x + (size_t)s * F_INC + lane * 2);
    a0 += v.x * w;
    a1 += v.y * w;
  }
  ushort2 o;
  o.x = f2bf(a0);
  o.y = f2bf(a1);
  *(ushort2*)(aggbf + (size_t)node * F_INC + lane * 2) = o;
}

// layer 2: one wave per node, F=512 bf16 in, bf16 out. lane holds 8 cols (16B).
__global__ __launch_bounds__(256)
void agg_gather2(const unsigned short* __restrict__ h1, const int* __restrict__ indptr,
                 const int* __restrict__ esrc, const float* __restrict__ ew,
                 unsigned short* __restrict__ aggbf) {
  int node = blockIdx.x * 4 + (threadIdx.x >> 6);
  if (node >= N_NODESC) return;
  int lane = threadIdx.x & 63;
  int beg = indptr[node], end = indptr[node + 1];
  float acc[8] = {};
  for (int j = beg; j < end; ++j) {
    int s = esrc[j];
    float w = ew[j];
    ushort8 v = *(const ushort8*)(h1 + (size_t)s * HIDC + lane * 8);
#pragma unroll
    for (int c = 0; c < 8; ++c) acc[c] += bf2f(v[c]) * w;
  }
  ushort8 o;
#pragma unroll
  for (int c = 0; c < 8; ++c) o[c] = f2bf(acc[c]);
  *(ushort8*)(aggbf + (size_t)node * HIDC + lane * 8) = o;
}

// ---------------- fp32 -> bf16 bulk convert (n % 4 == 0)
__global__ void f32_to_bf16(const float* __restrict__ src, unsigned short* __restrict__ dst, int n) {
  int i = (blockIdx.x * blockDim.x + threadIdx.x) * 4;
  if (i >= n) return;
  float4 v = *(const float4*)(src + i);
  ushort4 o;
  o.x = f2bf(v.x); o.y = f2bf(v.y); o.z = f2bf(v.z); o.w = f2bf(v.w);
  *(ushort4*)(dst + i) = o;
}

// ---------------- build B^T (bf16): WT[n][k] = k<S ? Wrel[k][n] : Wroot[k-S][n], n<512, K=2S
__global__ void build_WT(const float* __restrict__ Wrel, const float* __restrict__ Wroot,
                         unsigned short* __restrict__ WT, int S) {
  int K = 2 * S;
  int gid = blockIdx.x * blockDim.x + threadIdx.x;
  if (gid >= 512 * K) return;
  int n = gid / K;
  int k = gid - n * K;
  float v = (k < S) ? Wrel[(size_t)k * 512 + n] : Wroot[(size_t)(k - S) * 512 + n];
  WT[gid] = f2bf(v);
}

// ---------------- bf16 MFMA GEMM: Out = relu([A0|A1] @ BT^T + bias), Out bf16 [M][512]
__global__ __launch_bounds__(256, 2)
void gemm_bt_relu(const short* __restrict__ A0, const short* __restrict__ A1,
                  const short* __restrict__ BT, const float* __restrict__ bias,
                  unsigned short* __restrict__ Out, int M, int S) {
  const int K = 2 * S;
  __shared__ __align__(16) short As[128 * 64];
  __shared__ __align__(16) short Bs[128 * 64];
  const int m0 = blockIdx.x * 128;
  const int n0 = blockIdx.y * 128;
  const int tid = threadIdx.x;
  const int wave = tid >> 6;
  const int lane = tid & 63;
  const int quad = lane >> 4;
  const int r = lane & 15;
  const int wm = (wave >> 1) * 64;
  const int wn = (wave & 1) * 64;

  f32x4 acc[4][4] = {};

  const int nk = K >> 6;
  for (int kt = 0; kt < nk; ++kt) {
    const int kbase = kt << 6;
    const short* Ab;
    int koff;
    if (kbase < S) { Ab = A0; koff = kbase; } else { Ab = A1; koff = kbase - S; }
#pragma unroll
    for (int i = 0; i < 4; ++i) {
      int s = ((wave * 4 + i) << 6) + lane;     // 16B slot index
      int row = s >> 3;                          // tile row (m)
      int c = (s & 7) ^ (row & 7);               // global chunk (XOR swizzle)
      int rg = m0 + row; if (rg > M - 1) rg = M - 1;   // clamp OOB rows (discarded at store)
      const short* gp = Ab + (size_t)rg * S + koff + (c << 3);
      __builtin_amdgcn_global_load_lds((const __attribute__((address_space(1))) void*)gp,
                                       (__attribute__((address_space(3))) void*)&As[(wave * 4 + i) * 512],
                                       16, 0, 0);
    }
#pragma unroll
    for (int i = 0; i < 4; ++i) {
      int s = ((wave * 4 + i) << 6) + lane;
      int row = s >> 3;                          // tile row (n)
      int c = (s & 7) ^ (row & 7);
      const short* gp = BT + (size_t)(n0 + row) * K + kbase + (c << 3);
      __builtin_amdgcn_global_load_lds((const __attribute__((address_space(1))) void*)gp,
                                       (__attribute__((address_space(3))) void*)&Bs[(wave * 4 + i) * 512],
                                       16, 0, 0);
    }
    __syncthreads();
#pragma unroll
    for (int ks = 0; ks < 2; ++ks) {
      short8 af[4], bfr[4];
#pragma unroll
      for (int tm = 0; tm < 4; ++tm) {
        int ml = wm + tm * 16 + r;
        int c = (ks << 2) + quad;
        int slot = ml * 8 + (c ^ (ml & 7));
        af[tm] = *(const short8*)&As[slot * 8];
      }
#pragma unroll
      for (int tn = 0; tn < 4; ++tn) {
        int nl = wn + tn * 16 + r;
        int c = (ks << 2) + quad;
        int slot = nl * 8 + (c ^ (nl & 7));
        bfr[tn] = *(const short8*)&Bs[slot * 8];
      }
#pragma unroll
      for (int tm = 0; tm < 4; ++tm)
#pragma unroll
        for (int tn = 0; tn < 4; ++tn)
          acc[tm][tn] = __builtin_amdgcn_mfma_f32_16x16x32_bf16(af[tm], bfr[tn], acc[tm][tn], 0, 0, 0);
    }
    __syncthreads();
  }

#pragma unroll
  for (int tm = 0; tm < 4; ++tm) {
    int rowb = m0 + wm + tm * 16 + quad * 4;
#pragma unroll
    for (int tn = 0; tn < 4; ++tn) {
      int col = n0 + wn + tn * 16 + r;
      float bv = bias[col];
#pragma unroll
      for (int reg = 0; reg < 4; ++reg) {
        int rr = rowb + reg;
        if (rr < M) {
          float v = acc[tm][tn][reg] + bv;
          v = v > 0.f ? v : 0.f;
          Out[(size_t)rr * HIDC + col] = f2bf(v);
        }
      }
    }
  }
}

// ---------------- pool, stage 1: slab-parallel partial sums into gsum[64][512]
__global__ __launch_bounds__(256)
void pool_partial(const unsigned short* __restrict__ h2, const int* __restrict__ batch,
                  float* __restrict__ gsum) {
  int n0 = blockIdx.x * POOL_SLAB;
  int nend = n0 + POOL_SLAB;
  if (nend > N_NODESC) nend = N_NODESC;
  int col = threadIdx.x * 2;  // 256 threads, 2 cols each
  float a0 = 0.f, a1 = 0.f;
  int cur = batch[n0];
  for (int nd = n0; nd < nend; ++nd) {
    int g = batch[nd];
    if (g != cur) {
      atomicAdd(&gsum[cur * HIDC + col], a0);
      atomicAdd(&gsum[cur * HIDC + col + 1], a1);
      a0 = a1 = 0.f;
      cur = g;
    }
    ushort2 v = *(const ushort2*)(h2 + (size_t)nd * HIDC + col);
    a0 += bf2f(v.x);
    a1 += bf2f(v.y);
  }
  atomicAdd(&gsum[cur * HIDC + col], a0);
  atomicAdd(&gsum[cur * HIDC + col + 1], a1);
}

// ---------------- MLP head: divides sums by per-graph count (binary search on sorted batch)
__global__ void mlp_kernel(const float* __restrict__ gsum, const int* __restrict__ batch,
                           const float* __restrict__ Wl1, const float* __restrict__ bl1,
                           const float* __restrict__ Wl2, const float* __restrict__ bl2,
                           const float* __restrict__ Wl3, const float* __restrict__ bl3,
                           float* __restrict__ out) {
  int gi = blockIdx.x;
  int t = threadIdx.x;  // 64 threads
  __shared__ float h1s[64];
  __shared__ float h2s[16];
  int lo = 0, hi = N_NODESC;
  while (lo < hi) { int mid = (lo + hi) >> 1; if (batch[mid] < gi) lo = mid + 1; else hi = mid; }
  int start = lo;
  hi = N_NODESC;
  while (lo < hi) { int mid = (lo + hi) >> 1; if (batch[mid] < gi + 1) lo = mid + 1; else hi = mid; }
  float inv = 1.0f / fmaxf((float)(lo - start), 1.0f);
  const float* gr = gsum + gi * HIDC;
  float acc = bl1[t];
  for (int j = 0; j < 512; ++j) acc += gr[j] * inv * Wl1[j * 64 + t];
  h1s[t] = fmaxf(acc, 0.f);
  __syncthreads();
  if (t < 16) {
    float a = bl2[t];
    for (int j = 0; j < 64; ++j) a += h1s[j] * Wl2[j * 16 + t];
    h2s[t] = fmaxf(a, 0.f);
  }
  __syncthreads();
  if (t == 0) {
    float a = bl3[0];
    for (int j = 0; j < 16; ++j) a += h2s[j] * Wl3[j];
    out[gi] = a;
  }
}

extern "C" void kernel_launch(void* const* d_in, const int* in_sizes, int n_in,
                              void* d_out, int out_size, void* d_ws, size_t ws_size,
                              hipStream_t stream) {
  const float* x      = (const float*)d_in[0];
  const int*   ei     = (const int*)d_in[1];
  const float* ea     = (const float*)d_in[2];
  const int*   batch  = (const int*)d_in[3];
  const float* W1rel  = (const float*)d_in[4];
  const float* b1     = (const float*)d_in[5];
  const float* W1root = (const float*)d_in[6];
  const float* W2rel  = (const float*)d_in[7];
  const float* b2     = (const float*)d_in[8];
  const float* W2root = (const float*)d_in[9];
  const float* Wl1    = (const float*)d_in[10];
  const float* bl1    = (const float*)d_in[11];
  const float* Wl2    = (const float*)d_in[12];
  const float* bl2    = (const float*)d_in[13];
  const float* Wl3    = (const float*)d_in[14];
  const float* bl3    = (const float*)d_in[15];
  float* out = (float*)d_out;

  // workspace layout (bytes, all 16B-aligned):
  char* ws = (char*)d_ws;
  unsigned short* xbf    = (unsigned short*)(ws + 0);           //  6.4 MB
  unsigned short* agg1bf = (unsigned short*)(ws + 6400000);     //  6.4 MB
  unsigned short* h1     = (unsigned short*)(ws + 12800000);    // 25.6 MB
  unsigned short* agg2bf = (unsigned short*)(ws + 38400000);    // 25.6 MB
  unsigned short* h2     = (unsigned short*)(ws + 64000000);    // 25.6 MB
  unsigned short* W1T    = (unsigned short*)(ws + 89600000);    // 256 KB
  unsigned short* W2T    = (unsigned short*)(ws + 89862144);    //   1 MB
  float*          gsum   = (float*)(ws + 90910720);             // 128 KB
  int*            deg    = (int*)(ws + 91041792);               // 100 KB
  int*            cursor = (int*)(ws + 91141792);               // 100 KB
  int*            indptr = (int*)(ws + 91241792);               // 100 KB+4
  int*            esrc   = (int*)(ws + 91341808);               //  1.6 MB
  float*          ewgt   = (float*)(ws + 92941808);             //  1.6 MB

  // 0) CSR build
  hipMemsetAsync(deg, 0, N_NODESC * sizeof(int), stream);
  deg_kernel<<<(N_EDGESC + 255) / 256, 256, 0, stream>>>(ei, deg);
  scan_kernel<<<1, 1024, 0, stream>>>(deg, indptr, cursor);
  fill_kernel<<<(N_EDGESC + 255) / 256, 256, 0, stream>>>(ei, ea, cursor, esrc, ewgt);

  // 1) layer-1 aggregation (gather, no atomics) + x conversion + weight transposes
  agg_gather1<<<(N_NODESC + 3) / 4, 256, 0, stream>>>(x, indptr, esrc, ewgt, agg1bf);
  f32_to_bf16<<<(N_NODESC * F_INC / 4 + 255) / 256, 256, 0, stream>>>(x, xbf, N_NODESC * F_INC);
  build_WT<<<(512 * 256 + 255) / 256, 256, 0, stream>>>(W1rel, W1root, W1T, 128);
  build_WT<<<(512 * 1024 + 255) / 256, 256, 0, stream>>>(W2rel, W2root, W2T, 512);

  // 2) GEMM1: h1 = relu([agg1|x] @ [W1rel;W1root] + b1)   (M=25000, K=256, N=512)
  dim3 gg((N_NODESC + 127) / 128, 4);
  gemm_bt_relu<<<gg, 256, 0, stream>>>((const short*)agg1bf, (const short*)xbf,
                                       (const short*)W1T, b1, h1, N_NODESC, 128);

  // 3) layer-2 aggregation (gather, no atomics)
  agg_gather2<<<(N_NODESC + 3) / 4, 256, 0, stream>>>(h1, indptr, esrc, ewgt, agg2bf);

  // 4) GEMM2: h2 = relu([agg2|h1] @ [W2rel;W2root] + b2)   (M=25000, K=1024, N=512)
  gemm_bt_relu<<<gg, 256, 0, stream>>>((const short*)agg2bf, (const short*)h1,
                                       (const short*)W2T, b2, h2, N_NODESC, 512);

  // 5) mean pool (slab-parallel) + MLP head
  hipMemsetAsync(gsum, 0, N_GRAPHSC * HIDC * sizeof(float), stream);
  pool_partial<<<(N_NODESC + POOL_SLAB - 1) / POOL_SLAB, 256, 0, stream>>>(h2, batch, gsum);
  mlp_kernel<<<N_GRAPHSC, 64, 0, stream>>>(gsum, batch, Wl1, bl1, Wl2, bl2, Wl3, bl3, out);
}

// Round 4
// 370.213 us; speedup vs baseline: 9.7313x; 1.0813x over previous
//
#include <hip/hip_runtime.h>
#include <hip/hip_bf16.h>
#include <stdint.h>

#define N_NODESC 25000
#define N_EDGESC 400000
#define N_GRAPHSC 64
#define F_INC 128
#define HIDC 512
#define POOL_SLAB 64

typedef __attribute__((ext_vector_type(8))) short short8;
typedef __attribute__((ext_vector_type(8))) unsigned short ushort8;
typedef __attribute__((ext_vector_type(4))) float f32x4;

__device__ __forceinline__ float bf2f(unsigned short u) {
  return __uint_as_float(((unsigned)u) << 16);
}
__device__ __forceinline__ unsigned short f2bf(float f) {
  unsigned u = __float_as_uint(f);
  u += 0x7fffu + ((u >> 16) & 1u);
  return (unsigned short)(u >> 16);
}

// ================= CSR build (per launch; ~800K int atomics total) =================
__global__ void deg_kernel(const int* __restrict__ ei, int* __restrict__ deg) {
  int e = blockIdx.x * blockDim.x + threadIdx.x;
  if (e >= N_EDGESC) return;
  atomicAdd(&deg[ei[N_EDGESC + e]], 1);
}

// single-block exclusive scan of deg[25000] -> indptr[25001], copy to cursor
__global__ __launch_bounds__(1024)
void scan_kernel(const int* __restrict__ deg, int* __restrict__ indptr, int* __restrict__ cursor) {
  __shared__ int sums[1024];
  const int t = threadIdx.x;
  const int CH = (N_NODESC + 1023) / 1024;  // 25
  const int base = t * CH;
  int s = 0;
  for (int i = 0; i < CH; ++i) {
    int idx = base + i;
    if (idx < N_NODESC) s += deg[idx];
  }
  sums[t] = s;
  __syncthreads();
  for (int off = 1; off < 1024; off <<= 1) {
    int v = (t >= off) ? sums[t - off] : 0;
    __syncthreads();
    sums[t] += v;
    __syncthreads();
  }
  int run = (t > 0) ? sums[t - 1] : 0;
  for (int i = 0; i < CH; ++i) {
    int idx = base + i;
    if (idx < N_NODESC) {
      indptr[idx] = run;
      cursor[idx] = run;
      run += deg[idx];
    }
  }
  if (t == 0) indptr[N_NODESC] = sums[1023];
}

__global__ void fill_kernel(const int* __restrict__ ei, const float* __restrict__ ea,
                            int* __restrict__ cursor, int* __restrict__ esrc,
                            float* __restrict__ ew) {
  int e = blockIdx.x * blockDim.x + threadIdx.x;
  if (e >= N_EDGESC) return;
  int dst = ei[N_EDGESC + e];
  int pos = atomicAdd(&cursor[dst], 1);
  esrc[pos] = ei[e];
  ew[pos] = ea[e];
}

// ================= CSR gather aggregation (no atomics, ILP-pipelined) =================
// layer 1: one wave per node, F=128 bf16 in, bf16 out. lane holds 2 cols (4B).
// Edge meta loaded 64-at-a-time + __shfl broadcast; 4 independent row loads in flight.
__global__ __launch_bounds__(256)
void agg_gather1(const unsigned short* __restrict__ xbf, const int* __restrict__ indptr,
                 const int* __restrict__ esrc, const float* __restrict__ ew,
                 unsigned short* __restrict__ aggbf) {
  int node = blockIdx.x * 4 + (threadIdx.x >> 6);
  if (node >= N_NODESC) return;
  int lane = threadIdx.x & 63;
  int beg = indptr[node], end = indptr[node + 1];
  float a0 = 0.f, a1 = 0.f;
  const unsigned short* xb = xbf + lane * 2;
  for (int b = beg; b < end; b += 64) {
    int cnt = end - b;
    if (cnt > 64) cnt = 64;
    int sj = 0;
    float wj = 0.f;
    if (lane < cnt) { sj = esrc[b + lane]; wj = ew[b + lane]; }
    int j = 0;
    for (; j + 4 <= cnt; j += 4) {
      int s0 = __shfl(sj, j), s1 = __shfl(sj, j + 1), s2 = __shfl(sj, j + 2), s3 = __shfl(sj, j + 3);
      float w0 = __shfl(wj, j), w1 = __shfl(wj, j + 1), w2 = __shfl(wj, j + 2), w3 = __shfl(wj, j + 3);
      ushort2 v0 = *(const ushort2*)(xb + (size_t)s0 * F_INC);
      ushort2 v1 = *(const ushort2*)(xb + (size_t)s1 * F_INC);
      ushort2 v2 = *(const ushort2*)(xb + (size_t)s2 * F_INC);
      ushort2 v3 = *(const ushort2*)(xb + (size_t)s3 * F_INC);
      a0 += bf2f(v0.x) * w0; a1 += bf2f(v0.y) * w0;
      a0 += bf2f(v1.x) * w1; a1 += bf2f(v1.y) * w1;
      a0 += bf2f(v2.x) * w2; a1 += bf2f(v2.y) * w2;
      a0 += bf2f(v3.x) * w3; a1 += bf2f(v3.y) * w3;
    }
    for (; j < cnt; ++j) {
      int s = __shfl(sj, j);
      float w = __shfl(wj, j);
      ushort2 v = *(const ushort2*)(xb + (size_t)s * F_INC);
      a0 += bf2f(v.x) * w;
      a1 += bf2f(v.y) * w;
    }
  }
  ushort2 o;
  o.x = f2bf(a0);
  o.y = f2bf(a1);
  *(ushort2*)(aggbf + (size_t)node * F_INC + lane * 2) = o;
}

// layer 2: one wave per node, F=512 bf16 in, bf16 out. lane holds 8 cols (16B).
__global__ __launch_bounds__(256)
void agg_gather2(const unsigned short* __restrict__ h1, const int* __restrict__ indptr,
                 const int* __restrict__ esrc, const float* __restrict__ ew,
                 unsigned short* __restrict__ aggbf) {
  int node = blockIdx.x * 4 + (threadIdx.x >> 6);
  if (node >= N_NODESC) return;
  int lane = threadIdx.x & 63;
  int beg = indptr[node], end = indptr[node + 1];
  float acc[8] = {};
  const unsigned short* hb = h1 + lane * 8;
  for (int b = beg; b < end; b += 64) {
    int cnt = end - b;
    if (cnt > 64) cnt = 64;
    int sj = 0;
    float wj = 0.f;
    if (lane < cnt) { sj = esrc[b + lane]; wj = ew[b + lane]; }
    int j = 0;
    for (; j + 4 <= cnt; j += 4) {
      int s0 = __shfl(sj, j), s1 = __shfl(sj, j + 1), s2 = __shfl(sj, j + 2), s3 = __shfl(sj, j + 3);
      float w0 = __shfl(wj, j), w1 = __shfl(wj, j + 1), w2 = __shfl(wj, j + 2), w3 = __shfl(wj, j + 3);
      ushort8 v0 = *(const ushort8*)(hb + (size_t)s0 * HIDC);
      ushort8 v1 = *(const ushort8*)(hb + (size_t)s1 * HIDC);
      ushort8 v2 = *(const ushort8*)(hb + (size_t)s2 * HIDC);
      ushort8 v3 = *(const ushort8*)(hb + (size_t)s3 * HIDC);
#pragma unroll
      for (int c = 0; c < 8; ++c) acc[c] += bf2f(v0[c]) * w0;
#pragma unroll
      for (int c = 0; c < 8; ++c) acc[c] += bf2f(v1[c]) * w1;
#pragma unroll
      for (int c = 0; c < 8; ++c) acc[c] += bf2f(v2[c]) * w2;
#pragma unroll
      for (int c = 0; c < 8; ++c) acc[c] += bf2f(v3[c]) * w3;
    }
    for (; j < cnt; ++j) {
      int s = __shfl(sj, j);
      float w = __shfl(wj, j);
      ushort8 v = *(const ushort8*)(hb + (size_t)s * HIDC);
#pragma unroll
      for (int c = 0; c < 8; ++c) acc[c] += bf2f(v[c]) * w;
    }
  }
  ushort8 o;
#pragma unroll
  for (int c = 0; c < 8; ++c) o[c] = f2bf(acc[c]);
  *(ushort8*)(aggbf + (size_t)node * HIDC + lane * 8) = o;
}

// ---------------- fp32 -> bf16 bulk convert (n % 4 == 0)
__global__ void f32_to_bf16(const float* __restrict__ src, unsigned short* __restrict__ dst, int n) {
  int i = (blockIdx.x * blockDim.x + threadIdx.x) * 4;
  if (i >= n) return;
  float4 v = *(const float4*)(src + i);
  ushort4 o;
  o.x = f2bf(v.x); o.y = f2bf(v.y); o.z = f2bf(v.z); o.w = f2bf(v.w);
  *(ushort4*)(dst + i) = o;
}

// ---------------- build B^T (bf16): WT[n][k] = k<S ? Wrel[k][n] : Wroot[k-S][n], n<512, K=2S
__global__ void build_WT(const float* __restrict__ Wrel, const float* __restrict__ Wroot,
                         unsigned short* __restrict__ WT, int S) {
  int K = 2 * S;
  int gid = blockIdx.x * blockDim.x + threadIdx.x;
  if (gid >= 512 * K) return;
  int n = gid / K;
  int k = gid - n * K;
  float v = (k < S) ? Wrel[(size_t)k * 512 + n] : Wroot[(size_t)(k - S) * 512 + n];
  WT[gid] = f2bf(v);
}

// ---------------- bf16 MFMA GEMM: Out = relu([A0|A1] @ BT^T + bias), Out bf16 [M][512]
__global__ __launch_bounds__(256, 2)
void gemm_bt_relu(const short* __restrict__ A0, const short* __restrict__ A1,
                  const short* __restrict__ BT, const float* __restrict__ bias,
                  unsigned short* __restrict__ Out, int M, int S) {
  const int K = 2 * S;
  __shared__ __align__(16) short As[128 * 64];
  __shared__ __align__(16) short Bs[128 * 64];
  const int m0 = blockIdx.x * 128;
  const int n0 = blockIdx.y * 128;
  const int tid = threadIdx.x;
  const int wave = tid >> 6;
  const int lane = tid & 63;
  const int quad = lane >> 4;
  const int r = lane & 15;
  const int wm = (wave >> 1) * 64;
  const int wn = (wave & 1) * 64;

  f32x4 acc[4][4] = {};

  const int nk = K >> 6;
  for (int kt = 0; kt < nk; ++kt) {
    const int kbase = kt << 6;
    const short* Ab;
    int koff;
    if (kbase < S) { Ab = A0; koff = kbase; } else { Ab = A1; koff = kbase - S; }
#pragma unroll
    for (int i = 0; i < 4; ++i) {
      int s = ((wave * 4 + i) << 6) + lane;     // 16B slot index
      int row = s >> 3;                          // tile row (m)
      int c = (s & 7) ^ (row & 7);               // global chunk (XOR swizzle)
      int rg = m0 + row; if (rg > M - 1) rg = M - 1;   // clamp OOB rows (discarded at store)
      const short* gp = Ab + (size_t)rg * S + koff + (c << 3);
      __builtin_amdgcn_global_load_lds((const __attribute__((address_space(1))) void*)gp,
                                       (__attribute__((address_space(3))) void*)&As[(wave * 4 + i) * 512],
                                       16, 0, 0);
    }
#pragma unroll
    for (int i = 0; i < 4; ++i) {
      int s = ((wave * 4 + i) << 6) + lane;
      int row = s >> 3;                          // tile row (n)
      int c = (s & 7) ^ (row & 7);
      const short* gp = BT + (size_t)(n0 + row) * K + kbase + (c << 3);
      __builtin_amdgcn_global_load_lds((const __attribute__((address_space(1))) void*)gp,
                                       (__attribute__((address_space(3))) void*)&Bs[(wave * 4 + i) * 512],
                                       16, 0, 0);
    }
    __syncthreads();
#pragma unroll
    for (int ks = 0; ks < 2; ++ks) {
      short8 af[4], bfr[4];
#pragma unroll
      for (int tm = 0; tm < 4; ++tm) {
        int ml = wm + tm * 16 + r;
        int c = (ks << 2) + quad;
        int slot = ml * 8 + (c ^ (ml & 7));
        af[tm] = *(const short8*)&As[slot * 8];
      }
#pragma unroll
      for (int tn = 0; tn < 4; ++tn) {
        int nl = wn + tn * 16 + r;
        int c = (ks << 2) + quad;
        int slot = nl * 8 + (c ^ (nl & 7));
        bfr[tn] = *(const short8*)&Bs[slot * 8];
      }
#pragma unroll
      for (int tm = 0; tm < 4; ++tm)
#pragma unroll
        for (int tn = 0; tn < 4; ++tn)
          acc[tm][tn] = __builtin_amdgcn_mfma_f32_16x16x32_bf16(af[tm], bfr[tn], acc[tm][tn], 0, 0, 0);
    }
    __syncthreads();
  }

#pragma unroll
  for (int tm = 0; tm < 4; ++tm) {
    int rowb = m0 + wm + tm * 16 + quad * 4;
#pragma unroll
    for (int tn = 0; tn < 4; ++tn) {
      int col = n0 + wn + tn * 16 + r;
      float bv = bias[col];
#pragma unroll
      for (int reg = 0; reg < 4; ++reg) {
        int rr = rowb + reg;
        if (rr < M) {
          float v = acc[tm][tn][reg] + bv;
          v = v > 0.f ? v : 0.f;
          Out[(size_t)rr * HIDC + col] = f2bf(v);
        }
      }
    }
  }
}

// ---------------- pool, stage 1: slab-parallel partial sums into gsum[64][512]
__global__ __launch_bounds__(256)
void pool_partial(const unsigned short* __restrict__ h2, const int* __restrict__ batch,
                  float* __restrict__ gsum) {
  int n0 = blockIdx.x * POOL_SLAB;
  int nend = n0 + POOL_SLAB;
  if (nend > N_NODESC) nend = N_NODESC;
  int col = threadIdx.x * 2;  // 256 threads, 2 cols each
  float a0 = 0.f, a1 = 0.f;
  int cur = batch[n0];
  for (int nd = n0; nd < nend; ++nd) {
    int g = batch[nd];
    if (g != cur) {
      atomicAdd(&gsum[cur * HIDC + col], a0);
      atomicAdd(&gsum[cur * HIDC + col + 1], a1);
      a0 = a1 = 0.f;
      cur = g;
    }
    ushort2 v = *(const ushort2*)(h2 + (size_t)nd * HIDC + col);
    a0 += bf2f(v.x);
    a1 += bf2f(v.y);
  }
  atomicAdd(&gsum[cur * HIDC + col], a0);
  atomicAdd(&gsum[cur * HIDC + col + 1], a1);
}

// ---------------- MLP head: divides sums by per-graph count (binary search on sorted batch)
__global__ void mlp_kernel(const float* __restrict__ gsum, const int* __restrict__ batch,
                           const float* __restrict__ Wl1, const float* __restrict__ bl1,
                           const float* __restrict__ Wl2, const float* __restrict__ bl2,
                           const float* __restrict__ Wl3, const float* __restrict__ bl3,
                           float* __restrict__ out) {
  int gi = blockIdx.x;
  int t = threadIdx.x;  // 64 threads
  __shared__ float h1s[64];
  __shared__ float h2s[16];
  int lo = 0, hi = N_NODESC;
  while (lo < hi) { int mid = (lo + hi) >> 1; if (batch[mid] < gi) lo = mid + 1; else hi = mid; }
  int start = lo;
  hi = N_NODESC;
  while (lo < hi) { int mid = (lo + hi) >> 1; if (batch[mid] < gi + 1) lo = mid + 1; else hi = mid; }
  float inv = 1.0f / fmaxf((float)(lo - start), 1.0f);
  const float* gr = gsum + gi * HIDC;
  float acc = bl1[t];
  for (int j = 0; j < 512; ++j) acc += gr[j] * inv * Wl1[j * 64 + t];
  h1s[t] = fmaxf(acc, 0.f);
  __syncthreads();
  if (t < 16) {
    float a = bl2[t];
    for (int j = 0; j < 64; ++j) a += h1s[j] * Wl2[j * 16 + t];
    h2s[t] = fmaxf(a, 0.f);
  }
  __syncthreads();
  if (t == 0) {
    float a = bl3[0];
    for (int j = 0; j < 16; ++j) a += h2s[j] * Wl3[j];
    out[gi] = a;
  }
}

extern "C" void kernel_launch(void* const* d_in, const int* in_sizes, int n_in,
                              void* d_out, int out_size, void* d_ws, size_t ws_size,
                              hipStream_t stream) {
  const float* x      = (const float*)d_in[0];
  const int*   ei     = (const int*)d_in[1];
  const float* ea     = (const float*)d_in[2];
  const int*   batch  = (const int*)d_in[3];
  const float* W1rel  = (const float*)d_in[4];
  const float* b1     = (const float*)d_in[5];
  const float* W1root = (const float*)d_in[6];
  const float* W2rel  = (const float*)d_in[7];
  const float* b2     = (const float*)d_in[8];
  const float* W2root = (const float*)d_in[9];
  const float* Wl1    = (const float*)d_in[10];
  const float* bl1    = (const float*)d_in[11];
  const float* Wl2    = (const float*)d_in[12];
  const float* bl2    = (const float*)d_in[13];
  const float* Wl3    = (const float*)d_in[14];
  const float* bl3    = (const float*)d_in[15];
  float* out = (float*)d_out;

  // workspace layout (bytes, all 16B-aligned):
  char* ws = (char*)d_ws;
  unsigned short* xbf    = (unsigned short*)(ws + 0);           //  6.4 MB
  unsigned short* agg1bf = (unsigned short*)(ws + 6400000);     //  6.4 MB
  unsigned short* h1     = (unsigned short*)(ws + 12800000);    // 25.6 MB
  unsigned short* agg2bf = (unsigned short*)(ws + 38400000);    // 25.6 MB
  unsigned short* h2     = (unsigned short*)(ws + 64000000);    // 25.6 MB
  unsigned short* W1T    = (unsigned short*)(ws + 89600000);    // 256 KB
  unsigned short* W2T    = (unsigned short*)(ws + 89862144);    //   1 MB
  float*          gsum   = (float*)(ws + 90910720);             // 128 KB
  int*            deg    = (int*)(ws + 91041792);               // 100 KB
  int*            cursor = (int*)(ws + 91141792);               // 100 KB
  int*            indptr = (int*)(ws + 91241792);               // 100 KB+4
  int*            esrc   = (int*)(ws + 91341808);               //  1.6 MB
  float*          ewgt   = (float*)(ws + 92941808);             //  1.6 MB

  // 0) CSR build + x conversion (xbf needed by agg_gather1 now)
  hipMemsetAsync(deg, 0, N_NODESC * sizeof(int), stream);
  deg_kernel<<<(N_EDGESC + 255) / 256, 256, 0, stream>>>(ei, deg);
  f32_to_bf16<<<(N_NODESC * F_INC / 4 + 255) / 256, 256, 0, stream>>>(x, xbf, N_NODESC * F_INC);
  scan_kernel<<<1, 1024, 0, stream>>>(deg, indptr, cursor);
  fill_kernel<<<(N_EDGESC + 255) / 256, 256, 0, stream>>>(ei, ea, cursor, esrc, ewgt);

  // 1) layer-1 aggregation (bf16 gather, no atomics) + weight transposes
  agg_gather1<<<(N_NODESC + 3) / 4, 256, 0, stream>>>(xbf, indptr, esrc, ewgt, agg1bf);
  build_WT<<<(512 * 256 + 255) / 256, 256, 0, stream>>>(W1rel, W1root, W1T, 128);
  build_WT<<<(512 * 1024 + 255) / 256, 256, 0, stream>>>(W2rel, W2root, W2T, 512);

  // 2) GEMM1: h1 = relu([agg1|x] @ [W1rel;W1root] + b1)   (M=25000, K=256, N=512)
  dim3 gg((N_NODESC + 127) / 128, 4);
  gemm_bt_relu<<<gg, 256, 0, stream>>>((const short*)agg1bf, (const short*)xbf,
                                       (const short*)W1T, b1, h1, N_NODESC, 128);

  // 3) layer-2 aggregation (gather, no atomics)
  agg_gather2<<<(N_NODESC + 3) / 4, 256, 0, stream>>>(h1, indptr, esrc, ewgt, agg2bf);

  // 4) GEMM2: h2 = relu([agg2|h1] @ [W2rel;W2root] + b2)   (M=25000, K=1024, N=512)
  gemm_bt_relu<<<gg, 256, 0, stream>>>((const short*)agg2bf, (const short*)h1,
                                       (const short*)W2T, b2, h2, N_NODESC, 512);

  // 5) mean pool (slab-parallel) + MLP head
  hipMemsetAsync(gsum, 0, N_GRAPHSC * HIDC * sizeof(float), stream);
  pool_partial<<<(N_NODESC + POOL_SLAB - 1) / POOL_SLAB, 256, 0, stream>>>(h2, batch, gsum);
  mlp_kernel<<<N_GRAPHSC, 64, 0, stream>>>(gsum, batch, Wl1, bl1, Wl2, bl2, Wl3, bl3, out);
}

// Round 5
// 342.343 us; speedup vs baseline: 10.5236x; 1.0814x over previous
//
#include <hip/hip_runtime.h>
#include <hip/hip_bf16.h>
#include <stdint.h>

#define N_NODESC 25000
#define N_EDGESC 400000
#define N_GRAPHSC 64
#define F_INC 128
#define HIDC 512

typedef __attribute__((ext_vector_type(8))) short short8;
typedef __attribute__((ext_vector_type(8))) unsigned short ushort8;
typedef __attribute__((ext_vector_type(4))) float f32x4;

__device__ __forceinline__ float bf2f(unsigned short u) {
  return __uint_as_float(((unsigned)u) << 16);
}
__device__ __forceinline__ unsigned short f2bf(float f) {
  unsigned u = __float_as_uint(f);
  u += 0x7fffu + ((u >> 16) & 1u);
  return (unsigned short)(u >> 16);
}

// ================= prep: zero deg/gsum, x->bf16, both weight transposes (1 launch) ======
__global__ void prep_kernel(const float* __restrict__ x, const float* __restrict__ W1rel,
                            const float* __restrict__ W1root, const float* __restrict__ W2rel,
                            const float* __restrict__ W2root, unsigned short* __restrict__ xbf,
                            unsigned short* __restrict__ W1T, unsigned short* __restrict__ W2T,
                            int* __restrict__ deg, float* __restrict__ gsum) {
  int blk = blockIdx.x, t = threadIdx.x;
  if (blk < 98) {
    int i = blk * 256 + t;
    if (i < N_NODESC) deg[i] = 0;
  } else if (blk < 3223) {                       // 3125 blocks: 3.2M elems / 4
    int i = ((blk - 98) * 256 + t) * 4;
    float4 v = *(const float4*)(x + i);
    ushort4 o;
    o.x = f2bf(v.x); o.y = f2bf(v.y); o.z = f2bf(v.z); o.w = f2bf(v.w);
    *(ushort4*)(xbf + i) = o;
  } else if (blk < 3735) {                       // 512 blocks: W1T 512x256
    int gid = (blk - 3223) * 256 + t;
    int n = gid >> 8, k = gid & 255;
    float v = (k < 128) ? W1rel[(size_t)k * 512 + n] : W1root[(size_t)(k - 128) * 512 + n];
    W1T[gid] = f2bf(v);
  } else if (blk < 5783) {                       // 2048 blocks: W2T 512x1024
    int gid = (blk - 3735) * 256 + t;
    int n = gid >> 10, k = gid & 1023;
    float v = (k < 512) ? W2rel[(size_t)k * 512 + n] : W2root[(size_t)(k - 512) * 512 + n];
    W2T[gid] = f2bf(v);
  } else {                                       // 128 blocks: gsum 64x512
    int i = (blk - 5783) * 256 + t;
    if (i < N_GRAPHSC * HIDC) gsum[i] = 0.f;
  }
}

// ================= CSR build =================
__global__ void deg_kernel(const int* __restrict__ ei, int* __restrict__ deg) {
  int e = blockIdx.x * blockDim.x + threadIdx.x;
  if (e >= N_EDGESC) return;
  atomicAdd(&deg[ei[N_EDGESC + e]], 1);
}

__global__ __launch_bounds__(1024)
void scan_kernel(const int* __restrict__ deg, int* __restrict__ indptr, int* __restrict__ cursor) {
  __shared__ int sums[1024];
  const int t = threadIdx.x;
  const int CH = (N_NODESC + 1023) / 1024;  // 25
  const int base = t * CH;
  int s = 0;
  for (int i = 0; i < CH; ++i) {
    int idx = base + i;
    if (idx < N_NODESC) s += deg[idx];
  }
  sums[t] = s;
  __syncthreads();
  for (int off = 1; off < 1024; off <<= 1) {
    int v = (t >= off) ? sums[t - off] : 0;
    __syncthreads();
    sums[t] += v;
    __syncthreads();
  }
  int run = (t > 0) ? sums[t - 1] : 0;
  for (int i = 0; i < CH; ++i) {
    int idx = base + i;
    if (idx < N_NODESC) {
      indptr[idx] = run;
      cursor[idx] = run;
      run += deg[idx];
    }
  }
  if (t == 0) indptr[N_NODESC] = sums[1023];
}

__global__ void fill_kernel(const int* __restrict__ ei, const float* __restrict__ ea,
                            int* __restrict__ cursor, int* __restrict__ esrc,
                            float* __restrict__ ew) {
  int e = blockIdx.x * blockDim.x + threadIdx.x;
  if (e >= N_EDGESC) return;
  int dst = ei[N_EDGESC + e];
  int pos = atomicAdd(&cursor[dst], 1);
  esrc[pos] = ei[e];
  ew[pos] = ea[e];
}

// ================= CSR gather aggregation =================
// layer 1: one wave per node; half-wave (32 lanes x 8B = 256B) per edge row; 2 edges in
// flight per wave x 4-deep unroll. Halves combined by shfl_xor(32) at the end.
__global__ __launch_bounds__(256)
void agg_gather1(const unsigned short* __restrict__ xbf, const int* __restrict__ indptr,
                 const int* __restrict__ esrc, const float* __restrict__ ew,
                 unsigned short* __restrict__ aggbf) {
  int node = blockIdx.x * 4 + (threadIdx.x >> 6);
  if (node >= N_NODESC) return;
  int lane = threadIdx.x & 63;
  int half = lane >> 5;
  int l32 = lane & 31;
  int beg = indptr[node], end = indptr[node + 1];
  float a0 = 0.f, a1 = 0.f, a2 = 0.f, a3 = 0.f;
  const unsigned short* xb = xbf + l32 * 4;
  for (int b = beg; b < end; b += 64) {
    int cnt = end - b;
    if (cnt > 64) cnt = 64;
    int sj = 0;
    float wj = 0.f;
    if (lane < cnt) { sj = esrc[b + lane]; wj = ew[b + lane]; }
    int j = 0;
    for (; j + 8 <= cnt; j += 8) {
      int e0 = j + half, e1 = j + 2 + half, e2 = j + 4 + half, e3 = j + 6 + half;
      int s0 = __shfl(sj, e0), s1 = __shfl(sj, e1), s2 = __shfl(sj, e2), s3 = __shfl(sj, e3);
      float w0 = __shfl(wj, e0), w1 = __shfl(wj, e1), w2 = __shfl(wj, e2), w3 = __shfl(wj, e3);
      ushort4 v0 = *(const ushort4*)(xb + (size_t)s0 * F_INC);
      ushort4 v1 = *(const ushort4*)(xb + (size_t)s1 * F_INC);
      ushort4 v2 = *(const ushort4*)(xb + (size_t)s2 * F_INC);
      ushort4 v3 = *(const ushort4*)(xb + (size_t)s3 * F_INC);
      a0 += bf2f(v0.x) * w0; a1 += bf2f(v0.y) * w0; a2 += bf2f(v0.z) * w0; a3 += bf2f(v0.w) * w0;
      a0 += bf2f(v1.x) * w1; a1 += bf2f(v1.y) * w1; a2 += bf2f(v1.z) * w1; a3 += bf2f(v1.w) * w1;
      a0 += bf2f(v2.x) * w2; a1 += bf2f(v2.y) * w2; a2 += bf2f(v2.z) * w2; a3 += bf2f(v2.w) * w2;
      a0 += bf2f(v3.x) * w3; a1 += bf2f(v3.y) * w3; a2 += bf2f(v3.z) * w3; a3 += bf2f(v3.w) * w3;
    }
    for (; j < cnt; j += 2) {
      int e = j + half;
      int idx = e < cnt ? e : j;
      int s = __shfl(sj, idx);
      float w = __shfl(wj, idx);
      if (e < cnt) {
        ushort4 v = *(const ushort4*)(xb + (size_t)s * F_INC);
        a0 += bf2f(v.x) * w; a1 += bf2f(v.y) * w; a2 += bf2f(v.z) * w; a3 += bf2f(v.w) * w;
      }
    }
  }
  a0 += __shfl_xor(a0, 32);
  a1 += __shfl_xor(a1, 32);
  a2 += __shfl_xor(a2, 32);
  a3 += __shfl_xor(a3, 32);
  if (half == 0) {
    ushort4 o;
    o.x = f2bf(a0); o.y = f2bf(a1); o.z = f2bf(a2); o.w = f2bf(a3);
    *(ushort4*)(aggbf + (size_t)node * F_INC + l32 * 4) = o;
  }
}

// layer 2: TWO waves per node (split edge list), lane holds 8 cols (16B); LDS combine.
__global__ __launch_bounds__(256)
void agg_gather2(const unsigned short* __restrict__ h1, const int* __restrict__ indptr,
                 const int* __restrict__ esrc, const float* __restrict__ ew,
                 unsigned short* __restrict__ aggbf) {
  __shared__ float lds[2][HIDC];
  int pair = threadIdx.x >> 7;              // node slot in block
  int node = blockIdx.x * 2 + pair;
  int h = (threadIdx.x >> 6) & 1;           // which wave of the pair
  int lane = threadIdx.x & 63;
  bool valid = node < N_NODESC;
  int beg = 0, end = 0;
  if (valid) { beg = indptr[node]; end = indptr[node + 1]; }
  float acc[8] = {};
  const unsigned short* hb = h1 + lane * 8;
  for (int b = beg; b < end; b += 64) {
    int cnt = end - b;
    if (cnt > 64) cnt = 64;
    int sj = 0;
    float wj = 0.f;
    if (lane < cnt) { sj = esrc[b + lane]; wj = ew[b + lane]; }
    int j = 0;
    for (; j + 8 <= cnt; j += 8) {
      int base = j + 4 * h;                 // wave h takes 4 of each 8
      int s0 = __shfl(sj, base), s1 = __shfl(sj, base + 1);
      int s2 = __shfl(sj, base + 2), s3 = __shfl(sj, base + 3);
      float w0 = __shfl(wj, base), w1 = __shfl(wj, base + 1);
      float w2 = __shfl(wj, base + 2), w3 = __shfl(wj, base + 3);
      ushort8 v0 = *(const ushort8*)(hb + (size_t)s0 * HIDC);
      ushort8 v1 = *(const ushort8*)(hb + (size_t)s1 * HIDC);
      ushort8 v2 = *(const ushort8*)(hb + (size_t)s2 * HIDC);
      ushort8 v3 = *(const ushort8*)(hb + (size_t)s3 * HIDC);
#pragma unroll
      for (int c = 0; c < 8; ++c) acc[c] += bf2f(v0[c]) * w0;
#pragma unroll
      for (int c = 0; c < 8; ++c) acc[c] += bf2f(v1[c]) * w1;
#pragma unroll
      for (int c = 0; c < 8; ++c) acc[c] += bf2f(v2[c]) * w2;
#pragma unroll
      for (int c = 0; c < 8; ++c) acc[c] += bf2f(v3[c]) * w3;
    }
    if (h == 0) {
      for (; j < cnt; ++j) {
        int s = __shfl(sj, j);
        float w = __shfl(wj, j);
        ushort8 v = *(const ushort8*)(hb + (size_t)s * HIDC);
#pragma unroll
        for (int c = 0; c < 8; ++c) acc[c] += bf2f(v[c]) * w;
      }
    }
  }
  if (h == 1) {
#pragma unroll
    for (int c = 0; c < 8; ++c) lds[pair][lane * 8 + c] = acc[c];
  }
  __syncthreads();
  if (h == 0 && valid) {
    ushort8 o;
#pragma unroll
    for (int c = 0; c < 8; ++c) o[c] = f2bf(acc[c] + lds[pair][lane * 8 + c]);
    *(ushort8*)(aggbf + (size_t)node * HIDC + lane * 8) = o;
  }
}

// ---------------- bf16 MFMA GEMM: h1 = relu([A0|A1] @ BT^T + bias), Out bf16 [M][512]
__global__ __launch_bounds__(256, 2)
void gemm_bt_relu(const short* __restrict__ A0, const short* __restrict__ A1,
                  const short* __restrict__ BT, const float* __restrict__ bias,
                  unsigned short* __restrict__ Out, int M, int S) {
  const int K = 2 * S;
  __shared__ __align__(16) short As[128 * 64];
  __shared__ __align__(16) short Bs[128 * 64];
  const int m0 = blockIdx.x * 128;
  const int n0 = blockIdx.y * 128;
  const int tid = threadIdx.x;
  const int wave = tid >> 6;
  const int lane = tid & 63;
  const int quad = lane >> 4;
  const int r = lane & 15;
  const int wm = (wave >> 1) * 64;
  const int wn = (wave & 1) * 64;

  f32x4 acc[4][4] = {};

  const int nk = K >> 6;
  for (int kt = 0; kt < nk; ++kt) {
    const int kbase = kt << 6;
    const short* Ab;
    int koff;
    if (kbase < S) { Ab = A0; koff = kbase; } else { Ab = A1; koff = kbase - S; }
#pragma unroll
    for (int i = 0; i < 4; ++i) {
      int s = ((wave * 4 + i) << 6) + lane;
      int row = s >> 3;
      int c = (s & 7) ^ (row & 7);
      int rg = m0 + row; if (rg > M - 1) rg = M - 1;
      const short* gp = Ab + (size_t)rg * S + koff + (c << 3);
      __builtin_amdgcn_global_load_lds((const __attribute__((address_space(1))) void*)gp,
                                       (__attribute__((address_space(3))) void*)&As[(wave * 4 + i) * 512],
                                       16, 0, 0);
    }
#pragma unroll
    for (int i = 0; i < 4; ++i) {
      int s = ((wave * 4 + i) << 6) + lane;
      int row = s >> 3;
      int c = (s & 7) ^ (row & 7);
      const short* gp = BT + (size_t)(n0 + row) * K + kbase + (c << 3);
      __builtin_amdgcn_global_load_lds((const __attribute__((address_space(1))) void*)gp,
                                       (__attribute__((address_space(3))) void*)&Bs[(wave * 4 + i) * 512],
                                       16, 0, 0);
    }
    __syncthreads();
#pragma unroll
    for (int ks = 0; ks < 2; ++ks) {
      short8 af[4], bfr[4];
#pragma unroll
      for (int tm = 0; tm < 4; ++tm) {
        int ml = wm + tm * 16 + r;
        int c = (ks << 2) + quad;
        int slot = ml * 8 + (c ^ (ml & 7));
        af[tm] = *(const short8*)&As[slot * 8];
      }
#pragma unroll
      for (int tn = 0; tn < 4; ++tn) {
        int nl = wn + tn * 16 + r;
        int c = (ks << 2) + quad;
        int slot = nl * 8 + (c ^ (nl & 7));
        bfr[tn] = *(const short8*)&Bs[slot * 8];
      }
#pragma unroll
      for (int tm = 0; tm < 4; ++tm)
#pragma unroll
        for (int tn = 0; tn < 4; ++tn)
          acc[tm][tn] = __builtin_amdgcn_mfma_f32_16x16x32_bf16(af[tm], bfr[tn], acc[tm][tn], 0, 0, 0);
    }
    __syncthreads();
  }

#pragma unroll
  for (int tm = 0; tm < 4; ++tm) {
    int rowb = m0 + wm + tm * 16 + quad * 4;
#pragma unroll
    for (int tn = 0; tn < 4; ++tn) {
      int col = n0 + wn + tn * 16 + r;
      float bv = bias[col];
#pragma unroll
      for (int reg = 0; reg < 4; ++reg) {
        int rr = rowb + reg;
        if (rr < M) {
          float v = acc[tm][tn][reg] + bv;
          v = v > 0.f ? v : 0.f;
          Out[(size_t)rr * HIDC + col] = f2bf(v);
        }
      }
    }
  }
}

// ---------------- GEMM2 + fused mean-pool: gsum[g][col] += sum_rows relu(...) (no h2!)
__global__ __launch_bounds__(256, 2)
void gemm_bt_pool(const short* __restrict__ A0, const short* __restrict__ A1,
                  const short* __restrict__ BT, const float* __restrict__ bias,
                  const int* __restrict__ batch, float* __restrict__ gsum, int M, int S) {
  const int K = 2 * S;
  __shared__ __align__(16) short As[128 * 64];
  __shared__ __align__(16) short Bs[128 * 64];
  const int m0 = blockIdx.x * 128;
  const int n0 = blockIdx.y * 128;
  const int tid = threadIdx.x;
  const int wave = tid >> 6;
  const int lane = tid & 63;
  const int quad = lane >> 4;
  const int r = lane & 15;
  const int wm = (wave >> 1) * 64;
  const int wn = (wave & 1) * 64;

  f32x4 acc[4][4] = {};

  const int nk = K >> 6;
  for (int kt = 0; kt < nk; ++kt) {
    const int kbase = kt << 6;
    const short* Ab;
    int koff;
    if (kbase < S) { Ab = A0; koff = kbase; } else { Ab = A1; koff = kbase - S; }
#pragma unroll
    for (int i = 0; i < 4; ++i) {
      int s = ((wave * 4 + i) << 6) + lane;
      int row = s >> 3;
      int c = (s & 7) ^ (row & 7);
      int rg = m0 + row; if (rg > M - 1) rg = M - 1;
      const short* gp = Ab + (size_t)rg * S + koff + (c << 3);
      __builtin_amdgcn_global_load_lds((const __attribute__((address_space(1))) void*)gp,
                                       (__attribute__((address_space(3))) void*)&As[(wave * 4 + i) * 512],
                                       16, 0, 0);
    }
#pragma unroll
    for (int i = 0; i < 4; ++i) {
      int s = ((wave * 4 + i) << 6) + lane;
      int row = s >> 3;
      int c = (s & 7) ^ (row & 7);
      const short* gp = BT + (size_t)(n0 + row) * K + kbase + (c << 3);
      __builtin_amdgcn_global_load_lds((const __attribute__((address_space(1))) void*)gp,
                                       (__attribute__((address_space(3))) void*)&Bs[(wave * 4 + i) * 512],
                                       16, 0, 0);
    }
    __syncthreads();
#pragma unroll
    for (int ks = 0; ks < 2; ++ks) {
      short8 af[4], bfr[4];
#pragma unroll
      for (int tm = 0; tm < 4; ++tm) {
        int ml = wm + tm * 16 + r;
        int c = (ks << 2) + quad;
        int slot = ml * 8 + (c ^ (ml & 7));
        af[tm] = *(const short8*)&As[slot * 8];
      }
#pragma unroll
      for (int tn = 0; tn < 4; ++tn) {
        int nl = wn + tn * 16 + r;
        int c = (ks << 2) + quad;
        int slot = nl * 8 + (c ^ (nl & 7));
        bfr[tn] = *(const short8*)&Bs[slot * 8];
      }
#pragma unroll
      for (int tm = 0; tm < 4; ++tm)
#pragma unroll
        for (int tn = 0; tn < 4; ++tn)
          acc[tm][tn] = __builtin_amdgcn_mfma_f32_16x16x32_bf16(af[tm], bfr[tn], acc[tm][tn], 0, 0, 0);
    }
    __syncthreads();
  }

  // epilogue: relu(+bias), zero invalid rows, per-graph column sums -> atomicAdd(gsum)
  int gid[4][4];
#pragma unroll
  for (int tm = 0; tm < 4; ++tm) {
    int rowb = m0 + wm + tm * 16 + quad * 4;
#pragma unroll
    for (int reg = 0; reg < 4; ++reg) {
      int rr = rowb + reg;
      gid[tm][reg] = batch[rr < M ? rr : (M - 1)];
    }
#pragma unroll
    for (int tn = 0; tn < 4; ++tn) {
      float bv = bias[n0 + wn + tn * 16 + r];
#pragma unroll
      for (int reg = 0; reg < 4; ++reg) {
        int rr = rowb + reg;
        float v = acc[tm][tn][reg] + bv;
        v = v > 0.f ? v : 0.f;
        acc[tm][tn][reg] = (rr < M) ? v : 0.f;
      }
    }
  }
  int g_lo = batch[m0 < M ? m0 : (M - 1)];
  int g_hi = batch[(m0 + 127) < M ? (m0 + 127) : (M - 1)];
  for (int g = g_lo; g <= g_hi; ++g) {
#pragma unroll
    for (int tn = 0; tn < 4; ++tn) {
      float s = 0.f;
#pragma unroll
      for (int tm = 0; tm < 4; ++tm)
#pragma unroll
        for (int reg = 0; reg < 4; ++reg)
          s += (gid[tm][reg] == g) ? acc[tm][tn][reg] : 0.f;
      s += __shfl_xor(s, 16);
      s += __shfl_xor(s, 32);
      if (quad == 0)
        atomicAdd(&gsum[(size_t)g * HIDC + n0 + wn + tn * 16 + r], s);
    }
  }
}

// ---------------- MLP head: divides sums by per-graph count (binary search on sorted batch)
__global__ void mlp_kernel(const float* __restrict__ gsum, const int* __restrict__ batch,
                           const float* __restrict__ Wl1, const float* __restrict__ bl1,
                           const float* __restrict__ Wl2, const float* __restrict__ bl2,
                           const float* __restrict__ Wl3, const float* __restrict__ bl3,
                           float* __restrict__ out) {
  int gi = blockIdx.x;
  int t = threadIdx.x;  // 64 threads
  __shared__ float h1s[64];
  __shared__ float h2s[16];
  int lo = 0, hi = N_NODESC;
  while (lo < hi) { int mid = (lo + hi) >> 1; if (batch[mid] < gi) lo = mid + 1; else hi = mid; }
  int start = lo;
  hi = N_NODESC;
  while (lo < hi) { int mid = (lo + hi) >> 1; if (batch[mid] < gi + 1) lo = mid + 1; else hi = mid; }
  float inv = 1.0f / fmaxf((float)(lo - start), 1.0f);
  const float* gr = gsum + gi * HIDC;
  float acc = bl1[t];
  for (int j = 0; j < 512; ++j) acc += gr[j] * inv * Wl1[j * 64 + t];
  h1s[t] = fmaxf(acc, 0.f);
  __syncthreads();
  if (t < 16) {
    float a = bl2[t];
    for (int j = 0; j < 64; ++j) a += h1s[j] * Wl2[j * 16 + t];
    h2s[t] = fmaxf(a, 0.f);
  }
  __syncthreads();
  if (t == 0) {
    float a = bl3[0];
    for (int j = 0; j < 16; ++j) a += h2s[j] * Wl3[j];
    out[gi] = a;
  }
}

extern "C" void kernel_launch(void* const* d_in, const int* in_sizes, int n_in,
                              void* d_out, int out_size, void* d_ws, size_t ws_size,
                              hipStream_t stream) {
  const float* x      = (const float*)d_in[0];
  const int*   ei     = (const int*)d_in[1];
  const float* ea     = (const float*)d_in[2];
  const int*   batch  = (const int*)d_in[3];
  const float* W1rel  = (const float*)d_in[4];
  const float* b1     = (const float*)d_in[5];
  const float* W1root = (const float*)d_in[6];
  const float* W2rel  = (const float*)d_in[7];
  const float* b2     = (const float*)d_in[8];
  const float* W2root = (const float*)d_in[9];
  const float* Wl1    = (const float*)d_in[10];
  const float* bl1    = (const float*)d_in[11];
  const float* Wl2    = (const float*)d_in[12];
  const float* bl2    = (const float*)d_in[13];
  const float* Wl3    = (const float*)d_in[14];
  const float* bl3    = (const float*)d_in[15];
  float* out = (float*)d_out;

  // workspace layout (bytes, 16B-aligned):
  char* ws = (char*)d_ws;
  unsigned short* xbf    = (unsigned short*)(ws + 0);           //  6.4 MB
  unsigned short* agg1bf = (unsigned short*)(ws + 6400000);     //  6.4 MB
  unsigned short* h1     = (unsigned short*)(ws + 12800000);    // 25.6 MB
  unsigned short* agg2bf = (unsigned short*)(ws + 38400000);    // 25.6 MB
  unsigned short* W1T    = (unsigned short*)(ws + 64000000);    // 256 KB
  unsigned short* W2T    = (unsigned short*)(ws + 64262144);    //   1 MB
  float*          gsum   = (float*)(ws + 65310720);             // 128 KB
  int*            deg    = (int*)(ws + 65441792);               // 100 KB
  int*            cursor = (int*)(ws + 65541792);               // 100 KB
  int*            indptr = (int*)(ws + 65641792);               // 100 KB+16
  int*            esrc   = (int*)(ws + 65741808);               //  1.6 MB
  float*          ewgt   = (float*)(ws + 67341808);             //  1.6 MB

  // 0) prep (zero deg+gsum, x->bf16, W1T, W2T) + CSR build
  prep_kernel<<<5911, 256, 0, stream>>>(x, W1rel, W1root, W2rel, W2root,
                                        xbf, W1T, W2T, deg, gsum);
  deg_kernel<<<(N_EDGESC + 255) / 256, 256, 0, stream>>>(ei, deg);
  scan_kernel<<<1, 1024, 0, stream>>>(deg, indptr, cursor);
  fill_kernel<<<(N_EDGESC + 255) / 256, 256, 0, stream>>>(ei, ea, cursor, esrc, ewgt);

  // 1) layer-1 aggregation (bf16 gather, no atomics)
  agg_gather1<<<(N_NODESC + 3) / 4, 256, 0, stream>>>(xbf, indptr, esrc, ewgt, agg1bf);

  // 2) GEMM1: h1 = relu([agg1|x] @ [W1rel;W1root] + b1)   (M=25000, K=256, N=512)
  dim3 gg((N_NODESC + 127) / 128, 4);
  gemm_bt_relu<<<gg, 256, 0, stream>>>((const short*)agg1bf, (const short*)xbf,
                                       (const short*)W1T, b1, h1, N_NODESC, 128);

  // 3) layer-2 aggregation (gather, 2 waves/node)
  agg_gather2<<<(N_NODESC + 1) / 2, 256, 0, stream>>>(h1, indptr, esrc, ewgt, agg2bf);

  // 4) GEMM2 + fused mean-pool: gsum += per-graph col sums of relu([agg2|h1]@W2 + b2)
  gemm_bt_pool<<<gg, 256, 0, stream>>>((const short*)agg2bf, (const short*)h1,
                                       (const short*)W2T, b2, batch, gsum, N_NODESC, 512);

  // 5) MLP head (divides by counts)
  mlp_kernel<<<N_GRAPHSC, 64, 0, stream>>>(gsum, batch, Wl1, bl1, Wl2, bl2, Wl3, bl3, out);
}

// Round 6
// 336.369 us; speedup vs baseline: 10.7105x; 1.0178x over previous
//
#include <hip/hip_runtime.h>
#include <hip/hip_bf16.h>
#include <stdint.h>

#define N_NODESC 25000
#define N_EDGESC 400000
#define N_GRAPHSC 64
#define F_INC 128
#define HIDC 512

typedef __attribute__((ext_vector_type(8))) short short8;
typedef __attribute__((ext_vector_type(8))) unsigned short ushort8;
typedef __attribute__((ext_vector_type(4))) float f32x4;

__device__ __forceinline__ float bf2f(unsigned short u) {
  return __uint_as_float(((unsigned)u) << 16);
}
__device__ __forceinline__ unsigned short f2bf(float f) {
  unsigned u = __float_as_uint(f);
  u += 0x7fffu + ((u >> 16) & 1u);
  return (unsigned short)(u >> 16);
}

// ================= prep: zero deg/gsum, x->bf16 (1 launch) =================
__global__ void prep_kernel(const float* __restrict__ x, unsigned short* __restrict__ xbf,
                            int* __restrict__ deg, float* __restrict__ gsum) {
  int blk = blockIdx.x, t = threadIdx.x;
  if (blk < 98) {
    int i = blk * 256 + t;
    if (i < N_NODESC) deg[i] = 0;
  } else if (blk < 3223) {                       // 3125 blocks: 3.2M elems / 4
    int i = ((blk - 98) * 256 + t) * 4;
    float4 v = *(const float4*)(x + i);
    ushort4 o;
    o.x = f2bf(v.x); o.y = f2bf(v.y); o.z = f2bf(v.z); o.w = f2bf(v.w);
    *(ushort4*)(xbf + i) = o;
  } else {                                       // 128 blocks: gsum 64x512
    int i = (blk - 3223) * 256 + t;
    if (i < N_GRAPHSC * HIDC) gsum[i] = 0.f;
  }
}

// ================= weight transpose via LDS tiles (coalesced both sides) ==========
// W1T[512][256] from W1rel/W1root (128x512 each); W2T[512][1024] from W2rel/W2root
// (512x512 each). Tile 64(k) x 64(n). W2: 8 n-tiles x 16 k-tiles = 128 blocks; W1:
// 8 x 4 = 32 blocks. blocks 0..127 -> W2, 128..159 -> W1.
__global__ __launch_bounds__(256)
void wt_kernel(const float* __restrict__ W1rel, const float* __restrict__ W1root,
               const float* __restrict__ W2rel, const float* __restrict__ W2root,
               unsigned short* __restrict__ W1T, unsigned short* __restrict__ W2T) {
  __shared__ float tile[64][65];
  int blk = blockIdx.x;
  const float* src;
  unsigned short* dst;
  int n0, k0, Ksrc, Kout;
  if (blk < 128) {                               // W2: k-tiles 16, n-tiles 8
    int kt = blk >> 3, nt = blk & 7;
    k0 = kt * 64; n0 = nt * 64;
    src = (k0 < 512) ? (W2rel + (size_t)k0 * 512) : (W2root + (size_t)(k0 - 512) * 512);
    dst = W2T; Kout = 1024;
  } else {                                       // W1: k-tiles 4, n-tiles 8
    int b = blk - 128;
    int kt = b >> 3, nt = b & 7;
    k0 = kt * 64; n0 = nt * 64;
    src = (k0 < 128) ? (W1rel + (size_t)k0 * 512) : (W1root + (size_t)(k0 - 128) * 512);
    dst = W1T; Kout = 256;
  }
  (void)Ksrc;
  int c = threadIdx.x & 63;       // column within tile (n for read, k for write)
  int r4 = threadIdx.x >> 6;      // 4 rows per thread
#pragma unroll
  for (int rr = 0; rr < 64; rr += 4) {
    int row = rr + r4;
    tile[c][row] = src[(size_t)row * 512 + n0 + c];
  }
  __syncthreads();
#pragma unroll
  for (int rr = 0; rr < 64; rr += 4) {
    int nrow = rr + r4;
    dst[(size_t)(n0 + nrow) * Kout + k0 + c] = f2bf(tile[nrow][c]);
  }
}

// ================= CSR build =================
__global__ void deg_kernel(const int* __restrict__ ei, int* __restrict__ deg) {
  int e = blockIdx.x * blockDim.x + threadIdx.x;
  if (e >= N_EDGESC) return;
  atomicAdd(&deg[ei[N_EDGESC + e]], 1);
}

__global__ __launch_bounds__(1024)
void scan_kernel(const int* __restrict__ deg, int* __restrict__ indptr, int* __restrict__ cursor) {
  __shared__ int sums[1024];
  const int t = threadIdx.x;
  const int CH = (N_NODESC + 1023) / 1024;  // 25
  const int base = t * CH;
  int s = 0;
  for (int i = 0; i < CH; ++i) {
    int idx = base + i;
    if (idx < N_NODESC) s += deg[idx];
  }
  sums[t] = s;
  __syncthreads();
  for (int off = 1; off < 1024; off <<= 1) {
    int v = (t >= off) ? sums[t - off] : 0;
    __syncthreads();
    sums[t] += v;
    __syncthreads();
  }
  int run = (t > 0) ? sums[t - 1] : 0;
  for (int i = 0; i < CH; ++i) {
    int idx = base + i;
    if (idx < N_NODESC) {
      indptr[idx] = run;
      cursor[idx] = run;
      run += deg[idx];
    }
  }
  if (t == 0) indptr[N_NODESC] = sums[1023];
}

__global__ void fill_kernel(const int* __restrict__ ei, const float* __restrict__ ea,
                            int* __restrict__ cursor, int* __restrict__ esrc,
                            float* __restrict__ ew) {
  int e = blockIdx.x * blockDim.x + threadIdx.x;
  if (e >= N_EDGESC) return;
  int dst = ei[N_EDGESC + e];
  int pos = atomicAdd(&cursor[dst], 1);
  esrc[pos] = ei[e];
  ew[pos] = ea[e];
}

// ================= CSR gather aggregation =================
// layer 1: one wave per node; half-wave (32 lanes x 8B = 256B) per edge row; 8 edges in
// flight per wave. Halves combined by shfl_xor(32) at the end.
__global__ __launch_bounds__(256)
void agg_gather1(const unsigned short* __restrict__ xbf, const int* __restrict__ indptr,
                 const int* __restrict__ esrc, const float* __restrict__ ew,
                 unsigned short* __restrict__ aggbf) {
  int node = blockIdx.x * 4 + (threadIdx.x >> 6);
  if (node >= N_NODESC) return;
  int lane = threadIdx.x & 63;
  int half = lane >> 5;
  int l32 = lane & 31;
  int beg = indptr[node], end = indptr[node + 1];
  float a0 = 0.f, a1 = 0.f, a2 = 0.f, a3 = 0.f;
  const unsigned short* xb = xbf + l32 * 4;
  for (int b = beg; b < end; b += 64) {
    int cnt = end - b;
    if (cnt > 64) cnt = 64;
    int sj = 0;
    float wj = 0.f;
    if (lane < cnt) { sj = esrc[b + lane]; wj = ew[b + lane]; }
    int j = 0;
    for (; j + 16 <= cnt; j += 16) {
      int s[8];
      float w[8];
#pragma unroll
      for (int i = 0; i < 8; ++i) {
        int e = j + 2 * i + half;
        s[i] = __shfl(sj, e);
        w[i] = __shfl(wj, e);
      }
      ushort4 v[8];
#pragma unroll
      for (int i = 0; i < 8; ++i) v[i] = *(const ushort4*)(xb + (size_t)s[i] * F_INC);
#pragma unroll
      for (int i = 0; i < 8; ++i) {
        a0 += bf2f(v[i].x) * w[i]; a1 += bf2f(v[i].y) * w[i];
        a2 += bf2f(v[i].z) * w[i]; a3 += bf2f(v[i].w) * w[i];
      }
    }
    for (; j < cnt; j += 2) {
      int e = j + half;
      int idx = e < cnt ? e : j;
      int s = __shfl(sj, idx);
      float w = __shfl(wj, idx);
      if (e < cnt) {
        ushort4 v = *(const ushort4*)(xb + (size_t)s * F_INC);
        a0 += bf2f(v.x) * w; a1 += bf2f(v.y) * w; a2 += bf2f(v.z) * w; a3 += bf2f(v.w) * w;
      }
    }
  }
  a0 += __shfl_xor(a0, 32);
  a1 += __shfl_xor(a1, 32);
  a2 += __shfl_xor(a2, 32);
  a3 += __shfl_xor(a3, 32);
  if (half == 0) {
    ushort4 o;
    o.x = f2bf(a0); o.y = f2bf(a1); o.z = f2bf(a2); o.w = f2bf(a3);
    *(ushort4*)(aggbf + (size_t)node * F_INC + l32 * 4) = o;
  }
}

// layer 2: TWO waves per node (split edge list), lane holds 8 cols (16B); 8 loads in
// flight per wave; LDS combine.
__global__ __launch_bounds__(256)
void agg_gather2(const unsigned short* __restrict__ h1, const int* __restrict__ indptr,
                 const int* __restrict__ esrc, const float* __restrict__ ew,
                 unsigned short* __restrict__ aggbf) {
  __shared__ float lds[2][HIDC];
  int pair = threadIdx.x >> 7;              // node slot in block
  int node = blockIdx.x * 2 + pair;
  int h = (threadIdx.x >> 6) & 1;           // which wave of the pair
  int lane = threadIdx.x & 63;
  bool valid = node < N_NODESC;
  int beg = 0, end = 0;
  if (valid) { beg = indptr[node]; end = indptr[node + 1]; }
  float acc[8] = {};
  const unsigned short* hb = h1 + lane * 8;
  for (int b = beg; b < end; b += 64) {
    int cnt = end - b;
    if (cnt > 64) cnt = 64;
    int sj = 0;
    float wj = 0.f;
    if (lane < cnt) { sj = esrc[b + lane]; wj = ew[b + lane]; }
    int j = 0;
    for (; j + 16 <= cnt; j += 16) {
      int base = j + 8 * h;                 // wave h takes 8 of each 16
      int s[8];
      float w[8];
#pragma unroll
      for (int i = 0; i < 8; ++i) {
        s[i] = __shfl(sj, base + i);
        w[i] = __shfl(wj, base + i);
      }
      ushort8 v[8];
#pragma unroll
      for (int i = 0; i < 8; ++i) v[i] = *(const ushort8*)(hb + (size_t)s[i] * HIDC);
#pragma unroll
      for (int i = 0; i < 8; ++i)
#pragma unroll
        for (int c = 0; c < 8; ++c) acc[c] += bf2f(v[i][c]) * w[i];
    }
    if (h == 0) {
      for (; j < cnt; ++j) {
        int s = __shfl(sj, j);
        float w = __shfl(wj, j);
        ushort8 v = *(const ushort8*)(hb + (size_t)s * HIDC);
#pragma unroll
        for (int c = 0; c < 8; ++c) acc[c] += bf2f(v[c]) * w;
      }
    }
  }
  if (h == 1) {
#pragma unroll
    for (int c = 0; c < 8; ++c) lds[pair][lane * 8 + c] = acc[c];
  }
  __syncthreads();
  if (h == 0 && valid) {
    ushort8 o;
#pragma unroll
    for (int c = 0; c < 8; ++c) o[c] = f2bf(acc[c] + lds[pair][lane * 8 + c]);
    *(ushort8*)(aggbf + (size_t)node * HIDC + lane * 8) = o;
  }
}

// ---------------- bf16 MFMA GEMM: h1 = relu([A0|A1] @ BT^T + bias), Out bf16 [M][512]
__global__ __launch_bounds__(256, 3)
void gemm_bt_relu(const short* __restrict__ A0, const short* __restrict__ A1,
                  const short* __restrict__ BT, const float* __restrict__ bias,
                  unsigned short* __restrict__ Out, int M, int S) {
  const int K = 2 * S;
  __shared__ __align__(16) short As[128 * 64];
  __shared__ __align__(16) short Bs[128 * 64];
  const int m0 = blockIdx.x * 128;
  const int n0 = blockIdx.y * 128;
  const int tid = threadIdx.x;
  const int wave = tid >> 6;
  const int lane = tid & 63;
  const int quad = lane >> 4;
  const int r = lane & 15;
  const int wm = (wave >> 1) * 64;
  const int wn = (wave & 1) * 64;

  f32x4 acc[4][4] = {};

  const int nk = K >> 6;
  for (int kt = 0; kt < nk; ++kt) {
    const int kbase = kt << 6;
    const short* Ab;
    int koff;
    if (kbase < S) { Ab = A0; koff = kbase; } else { Ab = A1; koff = kbase - S; }
#pragma unroll
    for (int i = 0; i < 4; ++i) {
      int s = ((wave * 4 + i) << 6) + lane;
      int row = s >> 3;
      int c = (s & 7) ^ (row & 7);
      int rg = m0 + row; if (rg > M - 1) rg = M - 1;
      const short* gp = Ab + (size_t)rg * S + koff + (c << 3);
      __builtin_amdgcn_global_load_lds((const __attribute__((address_space(1))) void*)gp,
                                       (__attribute__((address_space(3))) void*)&As[(wave * 4 + i) * 512],
                                       16, 0, 0);
    }
#pragma unroll
    for (int i = 0; i < 4; ++i) {
      int s = ((wave * 4 + i) << 6) + lane;
      int row = s >> 3;
      int c = (s & 7) ^ (row & 7);
      const short* gp = BT + (size_t)(n0 + row) * K + kbase + (c << 3);
      __builtin_amdgcn_global_load_lds((const __attribute__((address_space(1))) void*)gp,
                                       (__attribute__((address_space(3))) void*)&Bs[(wave * 4 + i) * 512],
                                       16, 0, 0);
    }
    __syncthreads();
#pragma unroll
    for (int ks = 0; ks < 2; ++ks) {
      short8 af[4], bfr[4];
#pragma unroll
      for (int tm = 0; tm < 4; ++tm) {
        int ml = wm + tm * 16 + r;
        int c = (ks << 2) + quad;
        int slot = ml * 8 + (c ^ (ml & 7));
        af[tm] = *(const short8*)&As[slot * 8];
      }
#pragma unroll
      for (int tn = 0; tn < 4; ++tn) {
        int nl = wn + tn * 16 + r;
        int c = (ks << 2) + quad;
        int slot = nl * 8 + (c ^ (nl & 7));
        bfr[tn] = *(const short8*)&Bs[slot * 8];
      }
#pragma unroll
      for (int tm = 0; tm < 4; ++tm)
#pragma unroll
        for (int tn = 0; tn < 4; ++tn)
          acc[tm][tn] = __builtin_amdgcn_mfma_f32_16x16x32_bf16(af[tm], bfr[tn], acc[tm][tn], 0, 0, 0);
    }
    __syncthreads();
  }

#pragma unroll
  for (int tm = 0; tm < 4; ++tm) {
    int rowb = m0 + wm + tm * 16 + quad * 4;
#pragma unroll
    for (int tn = 0; tn < 4; ++tn) {
      int col = n0 + wn + tn * 16 + r;
      float bv = bias[col];
#pragma unroll
      for (int reg = 0; reg < 4; ++reg) {
        int rr = rowb + reg;
        if (rr < M) {
          float v = acc[tm][tn][reg] + bv;
          v = v > 0.f ? v : 0.f;
          Out[(size_t)rr * HIDC + col] = f2bf(v);
        }
      }
    }
  }
}

// ---------------- GEMM2 + fused mean-pool: gsum[g][col] += sum_rows relu(...) (no h2!)
__global__ __launch_bounds__(256, 3)
void gemm_bt_pool(const short* __restrict__ A0, const short* __restrict__ A1,
                  const short* __restrict__ BT, const float* __restrict__ bias,
                  const int* __restrict__ batch, float* __restrict__ gsum, int M, int S) {
  const int K = 2 * S;
  __shared__ __align__(16) short As[128 * 64];
  __shared__ __align__(16) short Bs[128 * 64];
  const int m0 = blockIdx.x * 128;
  const int n0 = blockIdx.y * 128;
  const int tid = threadIdx.x;
  const int wave = tid >> 6;
  const int lane = tid & 63;
  const int quad = lane >> 4;
  const int r = lane & 15;
  const int wm = (wave >> 1) * 64;
  const int wn = (wave & 1) * 64;

  f32x4 acc[4][4] = {};

  const int nk = K >> 6;
  for (int kt = 0; kt < nk; ++kt) {
    const int kbase = kt << 6;
    const short* Ab;
    int koff;
    if (kbase < S) { Ab = A0; koff = kbase; } else { Ab = A1; koff = kbase - S; }
#pragma unroll
    for (int i = 0; i < 4; ++i) {
      int s = ((wave * 4 + i) << 6) + lane;
      int row = s >> 3;
      int c = (s & 7) ^ (row & 7);
      int rg = m0 + row; if (rg > M - 1) rg = M - 1;
      const short* gp = Ab + (size_t)rg * S + koff + (c << 3);
      __builtin_amdgcn_global_load_lds((const __attribute__((address_space(1))) void*)gp,
                                       (__attribute__((address_space(3))) void*)&As[(wave * 4 + i) * 512],
                                       16, 0, 0);
    }
#pragma unroll
    for (int i = 0; i < 4; ++i) {
      int s = ((wave * 4 + i) << 6) + lane;
      int row = s >> 3;
      int c = (s & 7) ^ (row & 7);
      const short* gp = BT + (size_t)(n0 + row) * K + kbase + (c << 3);
      __builtin_amdgcn_global_load_lds((const __attribute__((address_space(1))) void*)gp,
                                       (__attribute__((address_space(3))) void*)&Bs[(wave * 4 + i) * 512],
                                       16, 0, 0);
    }
    __syncthreads();
#pragma unroll
    for (int ks = 0; ks < 2; ++ks) {
      short8 af[4], bfr[4];
#pragma unroll
      for (int tm = 0; tm < 4; ++tm) {
        int ml = wm + tm * 16 + r;
        int c = (ks << 2) + quad;
        int slot = ml * 8 + (c ^ (ml & 7));
        af[tm] = *(const short8*)&As[slot * 8];
      }
#pragma unroll
      for (int tn = 0; tn < 4; ++tn) {
        int nl = wn + tn * 16 + r;
        int c = (ks << 2) + quad;
        int slot = nl * 8 + (c ^ (nl & 7));
        bfr[tn] = *(const short8*)&Bs[slot * 8];
      }
#pragma unroll
      for (int tm = 0; tm < 4; ++tm)
#pragma unroll
        for (int tn = 0; tn < 4; ++tn)
          acc[tm][tn] = __builtin_amdgcn_mfma_f32_16x16x32_bf16(af[tm], bfr[tn], acc[tm][tn], 0, 0, 0);
    }
    __syncthreads();
  }

  // epilogue: relu(+bias), zero invalid rows, per-graph column sums -> atomicAdd(gsum)
  int gid[4][4];
#pragma unroll
  for (int tm = 0; tm < 4; ++tm) {
    int rowb = m0 + wm + tm * 16 + quad * 4;
#pragma unroll
    for (int reg = 0; reg < 4; ++reg) {
      int rr = rowb + reg;
      gid[tm][reg] = batch[rr < M ? rr : (M - 1)];
    }
#pragma unroll
    for (int tn = 0; tn < 4; ++tn) {
      float bv = bias[n0 + wn + tn * 16 + r];
#pragma unroll
      for (int reg = 0; reg < 4; ++reg) {
        int rr = rowb + reg;
        float v = acc[tm][tn][reg] + bv;
        v = v > 0.f ? v : 0.f;
        acc[tm][tn][reg] = (rr < M) ? v : 0.f;
      }
    }
  }
  int g_lo = batch[m0 < M ? m0 : (M - 1)];
  int g_hi = batch[(m0 + 127) < M ? (m0 + 127) : (M - 1)];
  for (int g = g_lo; g <= g_hi; ++g) {
#pragma unroll
    for (int tn = 0; tn < 4; ++tn) {
      float s = 0.f;
#pragma unroll
      for (int tm = 0; tm < 4; ++tm)
#pragma unroll
        for (int reg = 0; reg < 4; ++reg)
          s += (gid[tm][reg] == g) ? acc[tm][tn][reg] : 0.f;
      s += __shfl_xor(s, 16);
      s += __shfl_xor(s, 32);
      if (quad == 0)
        atomicAdd(&gsum[(size_t)g * HIDC + n0 + wn + tn * 16 + r], s);
    }
  }
}

// ---------------- MLP head (256 threads: 4-way split over the 512-dim input)
__global__ __launch_bounds__(256)
void mlp_kernel(const float* __restrict__ gsum, const int* __restrict__ batch,
                const float* __restrict__ Wl1, const float* __restrict__ bl1,
                const float* __restrict__ Wl2, const float* __restrict__ bl2,
                const float* __restrict__ Wl3, const float* __restrict__ bl3,
                float* __restrict__ out) {
  int gi = blockIdx.x;
  int t = threadIdx.x;
  int unit = t & 63;
  int part = t >> 6;  // 4 parts of 128
  __shared__ float red[4][64];
  __shared__ float h1s[64];
  __shared__ float h2s[16];
  int lo = 0, hi = N_NODESC;
  while (lo < hi) { int mid = (lo + hi) >> 1; if (batch[mid] < gi) lo = mid + 1; else hi = mid; }
  int start = lo;
  hi = N_NODESC;
  while (lo < hi) { int mid = (lo + hi) >> 1; if (batch[mid] < gi + 1) lo = mid + 1; else hi = mid; }
  float inv = 1.0f / fmaxf((float)(lo - start), 1.0f);
  const float* gr = gsum + gi * HIDC;
  float acc = 0.f;
  for (int j = part * 128; j < (part + 1) * 128; ++j)
    acc += gr[j] * Wl1[j * 64 + unit];
  red[part][unit] = acc;
  __syncthreads();
  if (t < 64) {
    float a = bl1[t] + (red[0][t] + red[1][t] + red[2][t] + red[3][t]) * inv;
    h1s[t] = fmaxf(a, 0.f);
  }
  __syncthreads();
  if (t < 16) {
    float a = bl2[t];
    for (int j = 0; j < 64; ++j) a += h1s[j] * Wl2[j * 16 + t];
    h2s[t] = fmaxf(a, 0.f);
  }
  __syncthreads();
  if (t == 0) {
    float a = bl3[0];
    for (int j = 0; j < 16; ++j) a += h2s[j] * Wl3[j];
    out[gi] = a;
  }
}

extern "C" void kernel_launch(void* const* d_in, const int* in_sizes, int n_in,
                              void* d_out, int out_size, void* d_ws, size_t ws_size,
                              hipStream_t stream) {
  const float* x      = (const float*)d_in[0];
  const int*   ei     = (const int*)d_in[1];
  const float* ea     = (const float*)d_in[2];
  const int*   batch  = (const int*)d_in[3];
  const float* W1rel  = (const float*)d_in[4];
  const float* b1     = (const float*)d_in[5];
  const float* W1root = (const float*)d_in[6];
  const float* W2rel  = (const float*)d_in[7];
  const float* b2     = (const float*)d_in[8];
  const float* W2root = (const float*)d_in[9];
  const float* Wl1    = (const float*)d_in[10];
  const float* bl1    = (const float*)d_in[11];
  const float* Wl2    = (const float*)d_in[12];
  const float* bl2    = (const float*)d_in[13];
  const float* Wl3    = (const float*)d_in[14];
  const float* bl3    = (const float*)d_in[15];
  float* out = (float*)d_out;

  // workspace layout (bytes, 16B-aligned):
  char* ws = (char*)d_ws;
  unsigned short* xbf    = (unsigned short*)(ws + 0);           //  6.4 MB
  unsigned short* agg1bf = (unsigned short*)(ws + 6400000);     //  6.4 MB
  unsigned short* h1     = (unsigned short*)(ws + 12800000);    // 25.6 MB
  unsigned short* agg2bf = (unsigned short*)(ws + 38400000);    // 25.6 MB
  unsigned short* W1T    = (unsigned short*)(ws + 64000000);    // 256 KB
  unsigned short* W2T    = (unsigned short*)(ws + 64262144);    //   1 MB
  float*          gsum   = (float*)(ws + 65310720);             // 128 KB
  int*            deg    = (int*)(ws + 65441792);               // 100 KB
  int*            cursor = (int*)(ws + 65541792);               // 100 KB
  int*            indptr = (int*)(ws + 65641792);               // 100 KB+16
  int*            esrc   = (int*)(ws + 65741808);               //  1.6 MB
  float*          ewgt   = (float*)(ws + 67341808);             //  1.6 MB

  // 0) prep (zero deg+gsum, x->bf16) + weight transposes + CSR build
  prep_kernel<<<3351, 256, 0, stream>>>(x, xbf, deg, gsum);
  wt_kernel<<<160, 256, 0, stream>>>(W1rel, W1root, W2rel, W2root, W1T, W2T);
  deg_kernel<<<(N_EDGESC + 255) / 256, 256, 0, stream>>>(ei, deg);
  scan_kernel<<<1, 1024, 0, stream>>>(deg, indptr, cursor);
  fill_kernel<<<(N_EDGESC + 255) / 256, 256, 0, stream>>>(ei, ea, cursor, esrc, ewgt);

  // 1) layer-1 aggregation (bf16 gather, no atomics)
  agg_gather1<<<(N_NODESC + 3) / 4, 256, 0, stream>>>(xbf, indptr, esrc, ewgt, agg1bf);

  // 2) GEMM1: h1 = relu([agg1|x] @ [W1rel;W1root] + b1)   (M=25000, K=256, N=512)
  dim3 gg((N_NODESC + 127) / 128, 4);
  gemm_bt_relu<<<gg, 256, 0, stream>>>((const short*)agg1bf, (const short*)xbf,
                                       (const short*)W1T, b1, h1, N_NODESC, 128);

  // 3) layer-2 aggregation (gather, 2 waves/node, 8-deep ILP)
  agg_gather2<<<(N_NODESC + 1) / 2, 256, 0, stream>>>(h1, indptr, esrc, ewgt, agg2bf);

  // 4) GEMM2 + fused mean-pool: gsum += per-graph col sums of relu([agg2|h1]@W2 + b2)
  gemm_bt_pool<<<gg, 256, 0, stream>>>((const short*)agg2bf, (const short*)h1,
                                       (const short*)W2T, b2, batch, gsum, N_NODESC, 512);

  // 5) MLP head (divides by counts)
  mlp_kernel<<<N_GRAPHSC, 256, 0, stream>>>(gsum, batch, Wl1, bl1, Wl2, bl2, Wl3, bl3, out);
}